// Round 3
// baseline (1525.451 us; speedup 1.0000x reference)
//
#include <hip/hip_runtime.h>
#include <math.h>

#define N_PTS 8192
#define ICP_STEPS 21      // STEPLIM + 1 scan iterations
#define ICP_TOL 1e-4

#define NB 256            // blocks; each owns 32 queries, scans all candidates
#define QPB 32            // queries per block
#define SLICES 8          // candidate slices per query (tid>>5)
#define CHUNK 2048        // candidates staged in LDS per chunk
#define NCHUNK 4          // 4 * 2048 = 8192

struct IcpState {
  double err;
  int done; int pad;
  double Rc[9];   // cumulative rotation (row-major): pc = Rc*p1 + tc
  double tc[3];
};

// ---------------------------------------------------------------------------
// init: state = identity transform, accumulators zeroed
// ---------------------------------------------------------------------------
__global__ __launch_bounds__(64) void icp_init(IcpState* __restrict__ st,
                                               double* __restrict__ acc,
                                               unsigned* __restrict__ ticket) {
  if (threadIdx.x == 0) {
    st->err = 0.0; st->done = 0;
    #pragma unroll
    for (int i = 0; i < 9; ++i) st->Rc[i] = (i % 4 == 0) ? 1.0 : 0.0;
    st->tc[0] = st->tc[1] = st->tc[2] = 0.0;
    #pragma unroll
    for (int i = 0; i < 16; ++i) acc[i] = 0.0;
    *ticket = 0u;
  }
}

// ---------------------------------------------------------------------------
// 3x3 Kabsch from raw sums (all double). s[0]=sum dmin, s[1..3]=sum src,
// s[4..6]=sum dst, s[7..15]=sum src_i*dst_j (row-major).
// R = V diag(1,1,detV) U~^T with right-handed U~; equals reference's
// V diag(1,1,sign(det U det V)) U^T.
// ---------------------------------------------------------------------------
__device__ void kabsch_solve(const double* s, double* R, double* T) {
  const double n = (double)N_PTS;
  double c1[3] = { s[1]/n, s[2]/n, s[3]/n };
  double c2[3] = { s[4]/n, s[5]/n, s[6]/n };
  double H[3][3];
  #pragma unroll
  for (int i = 0; i < 3; ++i)
    #pragma unroll
    for (int j = 0; j < 3; ++j)
      H[i][j] = s[7 + 3*i + j] - n * c1[i] * c2[j];

  double A[3][3];
  #pragma unroll
  for (int i = 0; i < 3; ++i)
    #pragma unroll
    for (int j = 0; j < 3; ++j)
      A[i][j] = H[0][i]*H[0][j] + H[1][i]*H[1][j] + H[2][i]*H[2][j];

  double V[3][3] = {{1,0,0},{0,1,0},{0,0,1}};
  for (int sweep = 0; sweep < 12; ++sweep) {
    double off = A[0][1]*A[0][1] + A[0][2]*A[0][2] + A[1][2]*A[1][2];
    double dg  = A[0][0]*A[0][0] + A[1][1]*A[1][1] + A[2][2]*A[2][2] + 1e-300;
    if (off <= 1e-30 * dg) break;
    #pragma unroll
    for (int pi = 0; pi < 3; ++pi) {
      const int p = (pi == 2) ? 1 : 0;
      const int q = (pi == 0) ? 1 : 2;
      double apq = A[p][q];
      if (fabs(apq) < 1e-300) continue;
      double tau = (A[q][q] - A[p][p]) / (2.0 * apq);
      double tt  = (tau >= 0.0 ? 1.0 : -1.0) / (fabs(tau) + sqrt(1.0 + tau*tau));
      double c   = 1.0 / sqrt(1.0 + tt*tt);
      double sn  = tt * c;
      A[p][p] -= tt*apq;
      A[q][q] += tt*apq;
      A[p][q] = A[q][p] = 0.0;
      const int r = 3 - p - q;
      double arp = A[r][p], arq = A[r][q];
      A[r][p] = A[p][r] = c*arp - sn*arq;
      A[r][q] = A[q][r] = sn*arp + c*arq;
      #pragma unroll
      for (int k = 0; k < 3; ++k) {
        double vkp = V[k][p], vkq = V[k][q];
        V[k][p] = c*vkp - sn*vkq;
        V[k][q] = sn*vkp + c*vkq;
      }
    }
  }
  double lam[3] = { A[0][0], A[1][1], A[2][2] };
  int ord[3] = {0,1,2};
  for (int i = 0; i < 2; ++i)
    for (int j = i+1; j < 3; ++j)
      if (lam[ord[j]] > lam[ord[i]]) { int t2 = ord[i]; ord[i] = ord[j]; ord[j] = t2; }
  double v0[3] = { V[0][ord[0]], V[1][ord[0]], V[2][ord[0]] };
  double v1[3] = { V[0][ord[1]], V[1][ord[1]], V[2][ord[1]] };
  double v2[3] = { V[0][ord[2]], V[1][ord[2]], V[2][ord[2]] };
  double detV = v0[0]*(v1[1]*v2[2] - v1[2]*v2[1])
              - v0[1]*(v1[0]*v2[2] - v1[2]*v2[0])
              + v0[2]*(v1[0]*v2[1] - v1[1]*v2[0]);
  detV = (detV >= 0.0) ? 1.0 : -1.0;

  double u0[3], u1[3], u2[3];
  #pragma unroll
  for (int i = 0; i < 3; ++i) u0[i] = H[i][0]*v0[0] + H[i][1]*v0[1] + H[i][2]*v0[2];
  double n0 = sqrt(u0[0]*u0[0] + u0[1]*u0[1] + u0[2]*u0[2]);
  if (!(n0 > 1e-150)) {
    for (int i = 0; i < 9; ++i) R[i] = (i % 4 == 0) ? 1.0 : 0.0;
    for (int i = 0; i < 3; ++i) T[i] = c2[i] - c1[i];
    return;
  }
  #pragma unroll
  for (int i = 0; i < 3; ++i) u0[i] /= n0;
  #pragma unroll
  for (int i = 0; i < 3; ++i) u1[i] = H[i][0]*v1[0] + H[i][1]*v1[1] + H[i][2]*v1[2];
  double d10 = u1[0]*u0[0] + u1[1]*u0[1] + u1[2]*u0[2];
  #pragma unroll
  for (int i = 0; i < 3; ++i) u1[i] -= d10 * u0[i];
  double n1 = sqrt(u1[0]*u1[0] + u1[1]*u1[1] + u1[2]*u1[2]);
  if (!(n1 > 1e-150)) {
    for (int i = 0; i < 9; ++i) R[i] = (i % 4 == 0) ? 1.0 : 0.0;
    for (int i = 0; i < 3; ++i) T[i] = c2[i] - c1[i];
    return;
  }
  #pragma unroll
  for (int i = 0; i < 3; ++i) u1[i] /= n1;
  u2[0] = u0[1]*u1[2] - u0[2]*u1[1];
  u2[1] = u0[2]*u1[0] - u0[0]*u1[2];
  u2[2] = u0[0]*u1[1] - u0[1]*u1[0];

  #pragma unroll
  for (int i = 0; i < 3; ++i)
    #pragma unroll
    for (int j = 0; j < 3; ++j)
      R[3*i + j] = v0[i]*u0[j] + v1[i]*u1[j] + detV * v2[i]*u2[j];
  #pragma unroll
  for (int i = 0; i < 3; ++i)
    T[i] = c2[i] - (R[3*i]*c1[0] + R[3*i+1]*c1[1] + R[3*i+2]*c1[2]);
}

// ---------------------------------------------------------------------------
// One fused ICP iteration:
//   NN (block-local full scan) -> slice combine -> pair sums -> atomicAdd ->
//   ticket -> last block: Kabsch solve, compose cumulative transform,
//   done-logic, write out, reset acc/ticket.
// Thread layout: q = tid&31 (query within block), s = tid>>5 (candidate slice).
// LDS reads are 2-distinct-address broadcasts per wave -> conflict-free.
// Next chunk's candidates are prefetched to registers before the compute
// phase so global latency hides under the VALU-dense inner loop.
// ---------------------------------------------------------------------------
__global__ __launch_bounds__(256) void icp_step(const float* __restrict__ p1,
                                                const float* __restrict__ p2,
                                                IcpState* __restrict__ st,
                                                double* __restrict__ acc,
                                                unsigned* __restrict__ ticket,
                                                float* __restrict__ out) {
  if (st->done) return;                      // uniform across grid
  __shared__ float4 cand[CHUNK];
  __shared__ unsigned long long packed[256];
  __shared__ double tot[16];
  __shared__ int lastFlag;

  const int tid  = threadIdx.x;
  const int qloc = tid & 31;
  const int s    = tid >> 5;
  const int q    = blockIdx.x * QPB + qloc;

  const double R0 = st->Rc[0], R1 = st->Rc[1], R2 = st->Rc[2];
  const double R3 = st->Rc[3], R4 = st->Rc[4], R5 = st->Rc[5];
  const double R6 = st->Rc[6], R7 = st->Rc[7], R8 = st->Rc[8];
  const double T0 = st->tc[0], T1 = st->tc[1], T2 = st->tc[2];

  // query position: fp32-rounded cumulative transform of p1 (matches ref's pc)
  double X = p1[3*q], Y = p1[3*q+1], Z = p1[3*q+2];
  const float qx = (float)(R0*X + R1*Y + R2*Z + T0);
  const float qy = (float)(R3*X + R4*Y + R5*Z + T1);
  const float qz = (float)(R6*X + R7*Y + R8*Z + T2);
  const float ax = -2.f*qx, ay = -2.f*qy, az = -2.f*qz;

  float best = __builtin_inff();
  int bidx = 0;

  // prefetch chunk 0 to registers
  float px[8], py[8], pz[8];
  #pragma unroll
  for (int k = 0; k < 8; ++k) {
    int c = k*256 + tid;
    px[k] = p2[3*c]; py[k] = p2[3*c+1]; pz[k] = p2[3*c+2];
  }

  #pragma unroll
  for (int cb = 0; cb < NCHUNK; ++cb) {
    // stage prefetched chunk into LDS (writes: 16B/lane consecutive, free)
    #pragma unroll
    for (int k = 0; k < 8; ++k) {
      float x = px[k], y = py[k], z = pz[k];
      cand[k*256 + tid] = make_float4(x, y, z, x*x + y*y + z*z);
    }
    __syncthreads();
    // issue next chunk's loads early -> latency hidden under inner loop
    if (cb < NCHUNK - 1) {
      #pragma unroll
      for (int k = 0; k < 8; ++k) {
        int c = (cb + 1)*CHUNK + k*256 + tid;
        px[k] = p2[3*c]; py[k] = p2[3*c+1]; pz[k] = p2[3*c+2];
      }
    }
    // inner scan: slice s covers within-chunk candidates [s*256, s*256+256)
    float bl = __builtin_inff();
    int il = 0;
    const int sbase = s << 8;
    #pragma unroll 8
    for (int i = 0; i < 256; ++i) {
      float4 c = cand[sbase + i];
      float d = fmaf(ax, c.x, fmaf(ay, c.y, fmaf(az, c.z, c.w)));
      if (d < bl) { bl = d; il = i; }
    }
    // strict < keeps the earlier (lower-index) chunk on exact ties
    if (bl < best) { best = bl; bidx = cb*CHUNK + sbase + il; }
    __syncthreads();
  }

  // combine the 8 slices per query: packed (ordered-float, idx) min ->
  // lowest distance, then lowest index (jnp.argmin tie semantics)
  unsigned u = __float_as_uint(best);
  u ^= (unsigned)((int)u >> 31) | 0x80000000u;   // monotone float->uint map
  packed[tid] = ((unsigned long long)u << 32) | (unsigned)bidx;
  __syncthreads();

  double v[16];
  if (tid < 64) {
    if (tid < 32) {
      unsigned long long m = packed[tid];
      #pragma unroll
      for (int ss = 1; ss < SLICES; ++ss) {
        unsigned long long o = packed[tid + (ss << 5)];
        m = (o < m) ? o : m;
      }
      unsigned idx = (unsigned)(m & 0xffffffffull);
      double dax = qx, day = qy, daz = qz;   // this thread's own query (tid==qloc)
      double bx = p2[3*idx], by = p2[3*idx+1], bz = p2[3*idx+2];
      double d2 = (dax*dax + day*day + daz*daz) + (bx*bx + by*by + bz*bz)
                - 2.0*(dax*bx + day*by + daz*bz);
      v[0]  = sqrt(fmax(d2, 1e-12));
      v[1]  = dax;    v[2]  = day;    v[3]  = daz;
      v[4]  = bx;     v[5]  = by;     v[6]  = bz;
      v[7]  = dax*bx; v[8]  = dax*by; v[9]  = dax*bz;
      v[10] = day*bx; v[11] = day*by; v[12] = day*bz;
      v[13] = daz*bx; v[14] = daz*by; v[15] = daz*bz;
    } else {
      #pragma unroll
      for (int t = 0; t < 16; ++t) v[t] = 0.0;
    }
    #pragma unroll
    for (int t = 0; t < 16; ++t) {
      double x = v[t];
      for (int o = 32; o > 0; o >>= 1) x += __shfl_down(x, o, 64);
      v[t] = x;
    }
    if (tid == 0) {
      #pragma unroll
      for (int t = 0; t < 16; ++t) atomicAdd(acc + t, v[t]);
    }
  }
  __threadfence();
  __syncthreads();
  if (tid == 0)
    lastFlag = (atomicAdd(ticket, 1u) == NB - 1) ? 1 : 0;
  __syncthreads();
  if (!lastFlag) return;

  // ---- last block: read totals coherently, solve, compose, emit, reset ----
  if (tid < 16) tot[tid] = atomicAdd(acc + tid, 0.0);   // device-scope read
  __syncthreads();
  if (tid == 0) {
    double sums[16];
    #pragma unroll
    for (int i = 0; i < 16; ++i) sums[i] = tot[i];
    double R[9], T[3];
    kabsch_solve(sums, R, T);
    // compose: pc_new = R*(Rc*p1 + tc) + T = (R*Rc)*p1 + (R*tc + T)
    double Rc[9] = {R0,R1,R2,R3,R4,R5,R6,R7,R8};
    double tc[3] = {T0,T1,T2};
    double Rn[9], tn[3];
    #pragma unroll
    for (int i = 0; i < 3; ++i) {
      #pragma unroll
      for (int j = 0; j < 3; ++j)
        Rn[3*i+j] = R[3*i+0]*Rc[0+j] + R[3*i+1]*Rc[3+j] + R[3*i+2]*Rc[6+j];
      tn[i] = R[3*i+0]*tc[0] + R[3*i+1]*tc[1] + R[3*i+2]*tc[2] + T[i];
    }
    #pragma unroll
    for (int i = 0; i < 9; ++i) st->Rc[i] = Rn[i];
    #pragma unroll
    for (int i = 0; i < 3; ++i) st->tc[i] = tn[i];
    double errnew = sums[0];                 // B == 1
    st->done = (fabs(st->err - errnew) < ICP_TOL) ? 1 : 0;
    st->err  = errnew;
    // out = [R | t] 3x4: kabsch(p1, Rc*p1+tc) == (Rc, tc) exactly.
    // Written every active iteration; the last active write is the answer.
    #pragma unroll
    for (int i = 0; i < 3; ++i) {
      out[4*i + 0] = (float)Rn[3*i + 0];
      out[4*i + 1] = (float)Rn[3*i + 1];
      out[4*i + 2] = (float)Rn[3*i + 2];
      out[4*i + 3] = (float)tn[i];
    }
    // reset accumulators for the next iteration
    #pragma unroll
    for (int i = 0; i < 16; ++i) acc[i] = 0.0;
    *ticket = 0u;
  }
}

// ---------------------------------------------------------------------------
extern "C" void kernel_launch(void* const* d_in, const int* in_sizes, int n_in,
                              void* d_out, int out_size, void* d_ws, size_t ws_size,
                              hipStream_t stream) {
  const float* p1 = (const float*)d_in[0];
  const float* p2 = (const float*)d_in[1];
  float* out = (float*)d_out;

  char* ws = (char*)d_ws;
  IcpState* st = (IcpState*)ws;                 // 128 B
  double* acc = (double*)(ws + 256);            // 128 B
  unsigned* ticket = (unsigned*)(ws + 512);     // 4 B

  icp_init<<<1, 64, 0, stream>>>(st, acc, ticket);
  for (int it = 0; it < ICP_STEPS; ++it)
    icp_step<<<NB, 256, 0, stream>>>(p1, p2, st, acc, ticket, out);
}

// Round 4
// 1521.453 us; speedup vs baseline: 1.0026x; 1.0026x over previous
//
#include <hip/hip_runtime.h>
#include <math.h>

#define N_PTS 8192
#define ICP_STEPS 21      // STEPLIM + 1 scan iterations
#define ICP_TOL 1e-4

#define NB 256            // one block per CU; block owns 32 queries
#define QPW 8             // queries per wave (each lane scans a 64-lane slice)
#define CHUNK 2048        // candidates staged in LDS per chunk (32 KiB)
#define NCHUNK 4          // 4 * 2048 = 8192

struct IcpCtl {
  double err;
  double Rc[9];     // cumulative rotation (row-major): pc = Rc*p1 + tc
  double tc[3];
  int done;
  unsigned ticket;  // reduce-completion ticket (selects solver block)
  unsigned cnt;     // grid barrier arrival count
  unsigned gen;     // grid barrier generation
};

// ---------------------------------------------------------------------------
// prep: p2aug = (x,y,z,|b|^2) float4; ctl/acc reset (runs every replay)
// ---------------------------------------------------------------------------
__global__ __launch_bounds__(256) void icp_prep(const float* __restrict__ p2,
                                                float4* __restrict__ p2aug,
                                                IcpCtl* __restrict__ ctl,
                                                double* __restrict__ acc) {
  int t = blockIdx.x * 256 + threadIdx.x;   // grid covers exactly N_PTS
  float x = p2[3*t], y = p2[3*t+1], z = p2[3*t+2];
  p2aug[t] = make_float4(x, y, z, fmaf(x, x, fmaf(y, y, z*z)));
  if (t == 0) {
    ctl->err = 0.0; ctl->done = 0;
    ctl->ticket = 0u; ctl->cnt = 0u; ctl->gen = 0u;
    #pragma unroll
    for (int i = 0; i < 9; ++i) ctl->Rc[i] = (i % 4 == 0) ? 1.0 : 0.0;
    ctl->tc[0] = ctl->tc[1] = ctl->tc[2] = 0.0;
    #pragma unroll
    for (int i = 0; i < 16; ++i) acc[i] = 0.0;
  }
}

// ---------------------------------------------------------------------------
// generation-counter grid barrier (cooperative launch guarantees residency)
// ---------------------------------------------------------------------------
__device__ __forceinline__ void grid_sync(IcpCtl* ctl) {
  __syncthreads();
  if (threadIdx.x == 0) {
    unsigned g = __hip_atomic_load(&ctl->gen, __ATOMIC_RELAXED, __HIP_MEMORY_SCOPE_AGENT);
    unsigned old = __hip_atomic_fetch_add(&ctl->cnt, 1u, __ATOMIC_ACQ_REL, __HIP_MEMORY_SCOPE_AGENT);
    if (old == NB - 1u) {
      __hip_atomic_store(&ctl->cnt, 0u, __ATOMIC_RELAXED, __HIP_MEMORY_SCOPE_AGENT);
      __hip_atomic_fetch_add(&ctl->gen, 1u, __ATOMIC_RELEASE, __HIP_MEMORY_SCOPE_AGENT);
    } else {
      while (__hip_atomic_load(&ctl->gen, __ATOMIC_ACQUIRE, __HIP_MEMORY_SCOPE_AGENT) == g)
        __builtin_amdgcn_s_sleep(2);
    }
  }
  __syncthreads();
}

// ---------------------------------------------------------------------------
// 3x3 Kabsch from raw sums (all double). s[0]=sum dmin, s[1..3]=sum src,
// s[4..6]=sum dst, s[7..15]=sum src_i*dst_j (row-major).  (proven in R2/R3)
// ---------------------------------------------------------------------------
__device__ void kabsch_solve(const double* s, double* R, double* T) {
  const double n = (double)N_PTS;
  double c1[3] = { s[1]/n, s[2]/n, s[3]/n };
  double c2[3] = { s[4]/n, s[5]/n, s[6]/n };
  double H[3][3];
  #pragma unroll
  for (int i = 0; i < 3; ++i)
    #pragma unroll
    for (int j = 0; j < 3; ++j)
      H[i][j] = s[7 + 3*i + j] - n * c1[i] * c2[j];

  double A[3][3];
  #pragma unroll
  for (int i = 0; i < 3; ++i)
    #pragma unroll
    for (int j = 0; j < 3; ++j)
      A[i][j] = H[0][i]*H[0][j] + H[1][i]*H[1][j] + H[2][i]*H[2][j];

  double V[3][3] = {{1,0,0},{0,1,0},{0,0,1}};
  for (int sweep = 0; sweep < 12; ++sweep) {
    double off = A[0][1]*A[0][1] + A[0][2]*A[0][2] + A[1][2]*A[1][2];
    double dg  = A[0][0]*A[0][0] + A[1][1]*A[1][1] + A[2][2]*A[2][2] + 1e-300;
    if (off <= 1e-30 * dg) break;
    #pragma unroll
    for (int pi = 0; pi < 3; ++pi) {
      const int p = (pi == 2) ? 1 : 0;
      const int q = (pi == 0) ? 1 : 2;
      double apq = A[p][q];
      if (fabs(apq) < 1e-300) continue;
      double tau = (A[q][q] - A[p][p]) / (2.0 * apq);
      double tt  = (tau >= 0.0 ? 1.0 : -1.0) / (fabs(tau) + sqrt(1.0 + tau*tau));
      double c   = 1.0 / sqrt(1.0 + tt*tt);
      double sn  = tt * c;
      A[p][p] -= tt*apq;
      A[q][q] += tt*apq;
      A[p][q] = A[q][p] = 0.0;
      const int r = 3 - p - q;
      double arp = A[r][p], arq = A[r][q];
      A[r][p] = A[p][r] = c*arp - sn*arq;
      A[r][q] = A[q][r] = sn*arp + c*arq;
      #pragma unroll
      for (int k = 0; k < 3; ++k) {
        double vkp = V[k][p], vkq = V[k][q];
        V[k][p] = c*vkp - sn*vkq;
        V[k][q] = sn*vkp + c*vkq;
      }
    }
  }
  double lam[3] = { A[0][0], A[1][1], A[2][2] };
  int ord[3] = {0,1,2};
  for (int i = 0; i < 2; ++i)
    for (int j = i+1; j < 3; ++j)
      if (lam[ord[j]] > lam[ord[i]]) { int t2 = ord[i]; ord[i] = ord[j]; ord[j] = t2; }
  double v0[3] = { V[0][ord[0]], V[1][ord[0]], V[2][ord[0]] };
  double v1[3] = { V[0][ord[1]], V[1][ord[1]], V[2][ord[1]] };
  double v2[3] = { V[0][ord[2]], V[1][ord[2]], V[2][ord[2]] };
  double detV = v0[0]*(v1[1]*v2[2] - v1[2]*v2[1])
              - v0[1]*(v1[0]*v2[2] - v1[2]*v2[0])
              + v0[2]*(v1[0]*v2[1] - v1[1]*v2[0]);
  detV = (detV >= 0.0) ? 1.0 : -1.0;

  double u0[3], u1[3], u2[3];
  #pragma unroll
  for (int i = 0; i < 3; ++i) u0[i] = H[i][0]*v0[0] + H[i][1]*v0[1] + H[i][2]*v0[2];
  double n0 = sqrt(u0[0]*u0[0] + u0[1]*u0[1] + u0[2]*u0[2]);
  if (!(n0 > 1e-150)) {
    for (int i = 0; i < 9; ++i) R[i] = (i % 4 == 0) ? 1.0 : 0.0;
    for (int i = 0; i < 3; ++i) T[i] = c2[i] - c1[i];
    return;
  }
  #pragma unroll
  for (int i = 0; i < 3; ++i) u0[i] /= n0;
  #pragma unroll
  for (int i = 0; i < 3; ++i) u1[i] = H[i][0]*v1[0] + H[i][1]*v1[1] + H[i][2]*v1[2];
  double d10 = u1[0]*u0[0] + u1[1]*u0[1] + u1[2]*u0[2];
  #pragma unroll
  for (int i = 0; i < 3; ++i) u1[i] -= d10 * u0[i];
  double n1 = sqrt(u1[0]*u1[0] + u1[1]*u1[1] + u1[2]*u1[2]);
  if (!(n1 > 1e-150)) {
    for (int i = 0; i < 9; ++i) R[i] = (i % 4 == 0) ? 1.0 : 0.0;
    for (int i = 0; i < 3; ++i) T[i] = c2[i] - c1[i];
    return;
  }
  #pragma unroll
  for (int i = 0; i < 3; ++i) u1[i] /= n1;
  u2[0] = u0[1]*u1[2] - u0[2]*u1[1];
  u2[1] = u0[2]*u1[0] - u0[0]*u1[2];
  u2[2] = u0[0]*u1[1] - u0[1]*u1[0];

  #pragma unroll
  for (int i = 0; i < 3; ++i)
    #pragma unroll
    for (int j = 0; j < 3; ++j)
      R[3*i + j] = v0[i]*u0[j] + v1[i]*u1[j] + detV * v2[i]*u2[j];
  #pragma unroll
  for (int i = 0; i < 3; ++i)
    T[i] = c2[i] - (R[3*i]*c1[0] + R[3*i+1]*c1[1] + R[3*i+2]*c1[2]);
}

// ---------------------------------------------------------------------------
// Persistent cooperative kernel: the whole ICP loop in one dispatch.
// Per iteration: NN (wave owns 8 queries, lanes = 64 candidate slices,
// LDS-chunked candidates, 8-way ILP) -> shfl_xor u64 butterfly argmin ->
// block pair-sums -> 16 atomicAdd -> ticket -> last block solves Kabsch,
// composes cumulative transform, writes out, resets -> grid_sync -> break
// on done (uniform).
// ---------------------------------------------------------------------------
__global__ __launch_bounds__(256) void icp_run(const float* __restrict__ p1,
                                               const float4* __restrict__ p2aug,
                                               IcpCtl* __restrict__ ctl,
                                               double* __restrict__ acc,
                                               float* __restrict__ out) {
  __shared__ float4 cand[CHUNK];          // 32 KiB
  __shared__ double pairbuf[32][16];      // 4 KiB
  __shared__ double stLds[13];
  __shared__ int sdone;

  const int tid  = threadIdx.x;
  const int lane = tid & 63;
  const int w    = tid >> 6;
  const int bid  = blockIdx.x;

  for (int it = 0; it < ICP_STEPS; ++it) {
    // ---- load cumulative transform + done flag (agent-scope coherent) ----
    if (tid < 13) {
      const double* p = (tid < 9) ? (ctl->Rc + tid) : (ctl->tc + (tid - 9));
      stLds[tid] = __hip_atomic_load(p, __ATOMIC_RELAXED, __HIP_MEMORY_SCOPE_AGENT);
    }
    if (tid == 14)
      sdone = __hip_atomic_load(&ctl->done, __ATOMIC_RELAXED, __HIP_MEMORY_SCOPE_AGENT);
    __syncthreads();
    if (sdone) break;                     // uniform across grid (post-sync read)

    const double R0 = stLds[0], R1 = stLds[1], R2 = stLds[2];
    const double R3 = stLds[3], R4 = stLds[4], R5 = stLds[5];
    const double R6 = stLds[6], R7 = stLds[7], R8 = stLds[8];
    const double T0 = stLds[9], T1 = stLds[10], T2 = stLds[11];

    // ---- query transforms: wave w owns queries qbase..qbase+7 (uniform) ----
    const int qbase = (bid << 5) + (w << 3);
    float qx[QPW], qy[QPW], qz[QPW], axv[QPW], ayv[QPW], azv[QPW], best[QPW];
    int bidx[QPW];
    #pragma unroll
    for (int j = 0; j < QPW; ++j) {
      const int q = qbase + j;
      const double X = (double)p1[3*q], Y = (double)p1[3*q+1], Z = (double)p1[3*q+2];
      qx[j] = (float)(R0*X + R1*Y + R2*Z + T0);
      qy[j] = (float)(R3*X + R4*Y + R5*Z + T1);
      qz[j] = (float)(R6*X + R7*Y + R8*Z + T2);
      axv[j] = -2.f*qx[j]; ayv[j] = -2.f*qy[j]; azv[j] = -2.f*qz[j];
      best[j] = __builtin_inff(); bidx[j] = 0;
    }

    // ---- NN scan: 4 chunks of 2048 candidates, reg-prefetch next chunk ----
    float4 pf[8];
    #pragma unroll
    for (int k = 0; k < 8; ++k) pf[k] = p2aug[(k << 8) + tid];
    for (int cb = 0; cb < NCHUNK; ++cb) {
      #pragma unroll
      for (int k = 0; k < 8; ++k) cand[(k << 8) + tid] = pf[k];
      __syncthreads();
      if (cb + 1 < NCHUNK) {
        #pragma unroll
        for (int k = 0; k < 8; ++k)
          pf[k] = p2aug[((cb + 1) << 11) + (k << 8) + tid];
      }
      const int cbase = cb << 11;
      #pragma unroll 8
      for (int k = 0; k < 32; ++k) {
        float4 c = cand[(k << 6) + lane];     // lane-contiguous: conflict-free
        const int cidx = cbase + (k << 6) + lane;
        #pragma unroll
        for (int j = 0; j < QPW; ++j) {
          float d = fmaf(axv[j], c.x, fmaf(ayv[j], c.y, fmaf(azv[j], c.z, c.w)));
          if (d < best[j]) { best[j] = d; bidx[j] = cidx; }
        }
      }
      __syncthreads();
    }

    // ---- cross-lane argmin: packed (ordered-dist, idx) u64 butterfly ----
    unsigned long long pk[QPW];
    #pragma unroll
    for (int j = 0; j < QPW; ++j) {
      unsigned u = __float_as_uint(best[j]);
      u ^= (unsigned)((int)u >> 31) | 0x80000000u;   // monotone float->uint
      pk[j] = ((unsigned long long)u << 32) | (unsigned)bidx[j];
    }
    #pragma unroll
    for (int j = 0; j < QPW; ++j) {
      #pragma unroll
      for (int o = 1; o < 64; o <<= 1) {
        unsigned long long other = __shfl_xor(pk[j], o, 64);
        pk[j] = (other < pk[j]) ? other : pk[j];     // lowest dist, then idx
      }
    }

    // ---- pair sums: lane j<8 of each wave handles its query j ----
    if (lane < QPW) {
      const int j = lane;
      const unsigned idx = (unsigned)(pk[j] & 0xffffffffull);
      float4 b4 = p2aug[idx];
      double ax = qx[j], ay = qy[j], az = qz[j];
      double bx = b4.x, by = b4.y, bz = b4.z;
      double d2 = (ax*ax + ay*ay + az*az) + (bx*bx + by*by + bz*bz)
                - 2.0*(ax*bx + ay*by + az*bz);
      double* pb = pairbuf[(w << 3) + j];
      pb[0]  = sqrt(fmax(d2, 1e-12));
      pb[1]  = ax;    pb[2]  = ay;    pb[3]  = az;
      pb[4]  = bx;    pb[5]  = by;    pb[6]  = bz;
      pb[7]  = ax*bx; pb[8]  = ax*by; pb[9]  = ax*bz;
      pb[10] = ay*bx; pb[11] = ay*by; pb[12] = ay*bz;
      pb[13] = az*bx; pb[14] = az*by; pb[15] = az*bz;
    }
    __syncthreads();

    // ---- wave 0: column sums -> 16 atomicAdd; tid0: ticket (acq_rel) ----
    if (tid < 16) {
      double s = 0.0;
      #pragma unroll
      for (int i = 0; i < 32; ++i) s += pairbuf[i][tid];
      atomicAdd(acc + tid, s);              // device-scope RMW
    }
    if (tid == 0) {
      // acq_rel: waits this wave's outstanding adds (vmcnt) before bumping
      unsigned old = __hip_atomic_fetch_add(&ctl->ticket, 1u,
                        __ATOMIC_ACQ_REL, __HIP_MEMORY_SCOPE_AGENT);
      if (old == NB - 1u) {
        // ---- solver: all 256 blocks' adds complete ----
        double s[16];
        #pragma unroll
        for (int i = 0; i < 16; ++i)
          s[i] = __hip_atomic_load(acc + i, __ATOMIC_RELAXED, __HIP_MEMORY_SCOPE_AGENT);
        double R[9], T[3];
        kabsch_solve(s, R, T);
        // compose: pc_new = R*(Rc*p1 + tc) + T = (R*Rc)*p1 + (R*tc + T)
        double Rc[9] = {R0,R1,R2,R3,R4,R5,R6,R7,R8};
        double tc[3] = {T0,T1,T2};
        double Rn[9], tn[3];
        #pragma unroll
        for (int i = 0; i < 3; ++i) {
          #pragma unroll
          for (int j = 0; j < 3; ++j)
            Rn[3*i+j] = R[3*i+0]*Rc[0+j] + R[3*i+1]*Rc[3+j] + R[3*i+2]*Rc[6+j];
          tn[i] = R[3*i+0]*tc[0] + R[3*i+1]*tc[1] + R[3*i+2]*tc[2] + T[i];
        }
        #pragma unroll
        for (int i = 0; i < 9; ++i)
          __hip_atomic_store(ctl->Rc + i, Rn[i], __ATOMIC_RELAXED, __HIP_MEMORY_SCOPE_AGENT);
        #pragma unroll
        for (int i = 0; i < 3; ++i)
          __hip_atomic_store(ctl->tc + i, tn[i], __ATOMIC_RELAXED, __HIP_MEMORY_SCOPE_AGENT);
        double errnew = s[0];               // B == 1
        double errold = __hip_atomic_load(&ctl->err, __ATOMIC_RELAXED, __HIP_MEMORY_SCOPE_AGENT);
        __hip_atomic_store(&ctl->err, errnew, __ATOMIC_RELAXED, __HIP_MEMORY_SCOPE_AGENT);
        __hip_atomic_store(&ctl->done, (fabs(errold - errnew) < ICP_TOL) ? 1 : 0,
                           __ATOMIC_RELAXED, __HIP_MEMORY_SCOPE_AGENT);
        // out = [Rc | tc] 3x4 (kabsch(p1, Rc*p1+tc) == (Rc,tc) exactly)
        #pragma unroll
        for (int i = 0; i < 3; ++i) {
          __hip_atomic_store(out + 4*i + 0, (float)Rn[3*i+0], __ATOMIC_RELAXED, __HIP_MEMORY_SCOPE_AGENT);
          __hip_atomic_store(out + 4*i + 1, (float)Rn[3*i+1], __ATOMIC_RELAXED, __HIP_MEMORY_SCOPE_AGENT);
          __hip_atomic_store(out + 4*i + 2, (float)Rn[3*i+2], __ATOMIC_RELAXED, __HIP_MEMORY_SCOPE_AGENT);
          __hip_atomic_store(out + 4*i + 3, (float)tn[i],     __ATOMIC_RELAXED, __HIP_MEMORY_SCOPE_AGENT);
        }
        // reset for next iteration (no one touches these until after sync)
        #pragma unroll
        for (int i = 0; i < 16; ++i)
          __hip_atomic_store(acc + i, 0.0, __ATOMIC_RELAXED, __HIP_MEMORY_SCOPE_AGENT);
        __hip_atomic_store(&ctl->ticket, 0u, __ATOMIC_RELAXED, __HIP_MEMORY_SCOPE_AGENT);
      }
    }

    grid_sync(ctl);   // release(writer) -> acquire(readers): st' visible
  }
}

// ---------------------------------------------------------------------------
extern "C" void kernel_launch(void* const* d_in, const int* in_sizes, int n_in,
                              void* d_out, int out_size, void* d_ws, size_t ws_size,
                              hipStream_t stream) {
  const float* p1 = (const float*)d_in[0];
  const float* p2 = (const float*)d_in[1];
  float* out = (float*)d_out;

  char* ws = (char*)d_ws;
  float4* p2aug = (float4*)ws;                       // 128 KiB
  IcpCtl* ctl   = (IcpCtl*)(ws + 128*1024);          // ~144 B
  double* acc   = (double*)(ws + 128*1024 + 512);    // 128 B

  icp_prep<<<N_PTS/256, 256, 0, stream>>>(p2, p2aug, ctl, acc);

  void* args[] = { (void*)&p1, (void*)&p2aug, (void*)&ctl, (void*)&acc, (void*)&out };
  hipLaunchCooperativeKernel((const void*)icp_run, dim3(NB), dim3(256),
                             args, 0, stream);
}

// Round 5
// 1054.838 us; speedup vs baseline: 1.4461x; 1.4424x over previous
//
#include <hip/hip_runtime.h>
#include <math.h>

#define N_PTS 8192
#define ICP_STEPS 21      // STEPLIM + 1 scan iterations
#define ICP_TOL 1e-4

#define NB 256            // one block per CU; block owns 32 queries
#define QPW 8             // queries per wave (lane-sliced candidates)
#define CHUNK 2048        // candidates staged in LDS per chunk (32 KiB)
#define NCHUNK 4          // 4 * 2048 = 8192

struct IcpCtl {
  double err;
  double Rc[9];     // cumulative rotation (row-major): pc = Rc*p1 + tc
  double tc[3];
  int done;
  unsigned ticket;  // reduce-completion ticket (selects solver block)
};

// ---------------------------------------------------------------------------
// prep: p2aug = (x,y,z,|b|^2) float4; ctl/acc reset (runs every replay)
// ---------------------------------------------------------------------------
__global__ __launch_bounds__(256) void icp_prep(const float* __restrict__ p2,
                                                float4* __restrict__ p2aug,
                                                IcpCtl* __restrict__ ctl,
                                                double* __restrict__ acc) {
  int t = blockIdx.x * 256 + threadIdx.x;   // grid covers exactly N_PTS
  float x = p2[3*t], y = p2[3*t+1], z = p2[3*t+2];
  p2aug[t] = make_float4(x, y, z, fmaf(x, x, fmaf(y, y, z*z)));
  if (t == 0) {
    ctl->err = 0.0; ctl->done = 0; ctl->ticket = 0u;
    #pragma unroll
    for (int i = 0; i < 9; ++i) ctl->Rc[i] = (i % 4 == 0) ? 1.0 : 0.0;
    ctl->tc[0] = ctl->tc[1] = ctl->tc[2] = 0.0;
    #pragma unroll
    for (int i = 0; i < 16; ++i) acc[i] = 0.0;
  }
}

// ---------------------------------------------------------------------------
// 3x3 Kabsch from raw sums (all double). s[0]=sum dmin, s[1..3]=sum src,
// s[4..6]=sum dst, s[7..15]=sum src_i*dst_j (row-major). Proven R2-R4.
// ---------------------------------------------------------------------------
__device__ void kabsch_solve(const double* s, double* R, double* T) {
  const double n = (double)N_PTS;
  double c1[3] = { s[1]/n, s[2]/n, s[3]/n };
  double c2[3] = { s[4]/n, s[5]/n, s[6]/n };
  double H[3][3];
  #pragma unroll
  for (int i = 0; i < 3; ++i)
    #pragma unroll
    for (int j = 0; j < 3; ++j)
      H[i][j] = s[7 + 3*i + j] - n * c1[i] * c2[j];

  double A[3][3];
  #pragma unroll
  for (int i = 0; i < 3; ++i)
    #pragma unroll
    for (int j = 0; j < 3; ++j)
      A[i][j] = H[0][i]*H[0][j] + H[1][i]*H[1][j] + H[2][i]*H[2][j];

  double V[3][3] = {{1,0,0},{0,1,0},{0,0,1}};
  for (int sweep = 0; sweep < 8; ++sweep) {
    double off = A[0][1]*A[0][1] + A[0][2]*A[0][2] + A[1][2]*A[1][2];
    double dg  = A[0][0]*A[0][0] + A[1][1]*A[1][1] + A[2][2]*A[2][2] + 1e-300;
    if (off <= 1e-30 * dg) break;
    #pragma unroll
    for (int pi = 0; pi < 3; ++pi) {
      const int p = (pi == 2) ? 1 : 0;
      const int q = (pi == 0) ? 1 : 2;
      double apq = A[p][q];
      if (fabs(apq) < 1e-300) continue;
      double tau = (A[q][q] - A[p][p]) / (2.0 * apq);
      double tt  = (tau >= 0.0 ? 1.0 : -1.0) / (fabs(tau) + sqrt(1.0 + tau*tau));
      double c   = 1.0 / sqrt(1.0 + tt*tt);
      double sn  = tt * c;
      A[p][p] -= tt*apq;
      A[q][q] += tt*apq;
      A[p][q] = A[q][p] = 0.0;
      const int r = 3 - p - q;
      double arp = A[r][p], arq = A[r][q];
      A[r][p] = A[p][r] = c*arp - sn*arq;
      A[r][q] = A[q][r] = sn*arp + c*arq;
      #pragma unroll
      for (int k = 0; k < 3; ++k) {
        double vkp = V[k][p], vkq = V[k][q];
        V[k][p] = c*vkp - sn*vkq;
        V[k][q] = sn*vkp + c*vkq;
      }
    }
  }
  double lam[3] = { A[0][0], A[1][1], A[2][2] };
  int ord[3] = {0,1,2};
  for (int i = 0; i < 2; ++i)
    for (int j = i+1; j < 3; ++j)
      if (lam[ord[j]] > lam[ord[i]]) { int t2 = ord[i]; ord[i] = ord[j]; ord[j] = t2; }
  double v0[3] = { V[0][ord[0]], V[1][ord[0]], V[2][ord[0]] };
  double v1[3] = { V[0][ord[1]], V[1][ord[1]], V[2][ord[1]] };
  double v2[3] = { V[0][ord[2]], V[1][ord[2]], V[2][ord[2]] };
  double detV = v0[0]*(v1[1]*v2[2] - v1[2]*v2[1])
              - v0[1]*(v1[0]*v2[2] - v1[2]*v2[0])
              + v0[2]*(v1[0]*v2[1] - v1[1]*v2[0]);
  detV = (detV >= 0.0) ? 1.0 : -1.0;

  double u0[3], u1[3], u2[3];
  #pragma unroll
  for (int i = 0; i < 3; ++i) u0[i] = H[i][0]*v0[0] + H[i][1]*v0[1] + H[i][2]*v0[2];
  double n0 = sqrt(u0[0]*u0[0] + u0[1]*u0[1] + u0[2]*u0[2]);
  if (!(n0 > 1e-150)) {
    for (int i = 0; i < 9; ++i) R[i] = (i % 4 == 0) ? 1.0 : 0.0;
    for (int i = 0; i < 3; ++i) T[i] = c2[i] - c1[i];
    return;
  }
  #pragma unroll
  for (int i = 0; i < 3; ++i) u0[i] /= n0;
  #pragma unroll
  for (int i = 0; i < 3; ++i) u1[i] = H[i][0]*v1[0] + H[i][1]*v1[1] + H[i][2]*v1[2];
  double d10 = u1[0]*u0[0] + u1[1]*u0[1] + u1[2]*u0[2];
  #pragma unroll
  for (int i = 0; i < 3; ++i) u1[i] -= d10 * u0[i];
  double n1 = sqrt(u1[0]*u1[0] + u1[1]*u1[1] + u1[2]*u1[2]);
  if (!(n1 > 1e-150)) {
    for (int i = 0; i < 9; ++i) R[i] = (i % 4 == 0) ? 1.0 : 0.0;
    for (int i = 0; i < 3; ++i) T[i] = c2[i] - c1[i];
    return;
  }
  #pragma unroll
  for (int i = 0; i < 3; ++i) u1[i] /= n1;
  u2[0] = u0[1]*u1[2] - u0[2]*u1[1];
  u2[1] = u0[2]*u1[0] - u0[0]*u1[2];
  u2[2] = u0[0]*u1[1] - u0[1]*u1[0];

  #pragma unroll
  for (int i = 0; i < 3; ++i)
    #pragma unroll
    for (int j = 0; j < 3; ++j)
      R[3*i + j] = v0[i]*u0[j] + v1[i]*u1[j] + detV * v2[i]*u2[j];
  #pragma unroll
  for (int i = 0; i < 3; ++i)
    T[i] = c2[i] - (R[3*i]*c1[0] + R[3*i+1]*c1[1] + R[3*i+2]*c1[2]);
}

// ---------------------------------------------------------------------------
// One fused ICP iteration (one dispatch):
//   NN full scan (wave owns 8 queries, 64 lanes = candidate slices, LDS
//   chunks, 8-way ILP) -> shfl_xor u64 butterfly argmin -> block pair sums
//   (padded LDS, conflict-free) -> 16 atomicAdd -> ticket -> last block:
//   Kabsch solve, compose cumulative transform, done-logic, write out,
//   reset acc/ticket. Dispatch boundary provides cross-XCD coherence.
// ---------------------------------------------------------------------------
__global__ __launch_bounds__(256) void icp_iter(const float* __restrict__ p1,
                                                const float4* __restrict__ p2aug,
                                                IcpCtl* __restrict__ ctl,
                                                double* __restrict__ acc,
                                                float* __restrict__ out) {
  if (ctl->done) return;                    // uniform across grid
  __shared__ float4 cand[CHUNK];            // 32 KiB
  __shared__ double pairbuf[32][17];        // +1 pad: kills 32-way conflicts
  __shared__ double tot[16];
  __shared__ int lastFlag;

  const int tid  = threadIdx.x;
  const int lane = tid & 63;
  const int w    = tid >> 6;

  const double R0 = ctl->Rc[0], R1 = ctl->Rc[1], R2 = ctl->Rc[2];
  const double R3 = ctl->Rc[3], R4 = ctl->Rc[4], R5 = ctl->Rc[5];
  const double R6 = ctl->Rc[6], R7 = ctl->Rc[7], R8 = ctl->Rc[8];
  const double T0 = ctl->tc[0], T1 = ctl->tc[1], T2 = ctl->tc[2];

  // ---- wave w owns queries qbase..qbase+7 (uniform across its lanes) ----
  const int qbase = (blockIdx.x << 5) + (w << 3);
  float qx[QPW], qy[QPW], qz[QPW], axv[QPW], ayv[QPW], azv[QPW], best[QPW];
  int bidx[QPW];
  #pragma unroll
  for (int j = 0; j < QPW; ++j) {
    const int q = qbase + j;
    const double X = (double)p1[3*q], Y = (double)p1[3*q+1], Z = (double)p1[3*q+2];
    qx[j] = (float)(R0*X + R1*Y + R2*Z + T0);   // fp32-rounded, matches ref pc
    qy[j] = (float)(R3*X + R4*Y + R5*Z + T1);
    qz[j] = (float)(R6*X + R7*Y + R8*Z + T2);
    axv[j] = -2.f*qx[j]; ayv[j] = -2.f*qy[j]; azv[j] = -2.f*qz[j];
    best[j] = __builtin_inff(); bidx[j] = 0;
  }

  // ---- NN scan: 4 chunks of 2048 candidates, reg-prefetch next chunk ----
  float4 pf[8];
  #pragma unroll
  for (int k = 0; k < 8; ++k) pf[k] = p2aug[(k << 8) + tid];
  for (int cb = 0; cb < NCHUNK; ++cb) {
    #pragma unroll
    for (int k = 0; k < 8; ++k) cand[(k << 8) + tid] = pf[k];
    __syncthreads();
    if (cb + 1 < NCHUNK) {
      #pragma unroll
      for (int k = 0; k < 8; ++k)
        pf[k] = p2aug[((cb + 1) << 11) + (k << 8) + tid];
    }
    const int cbase = cb << 11;
    #pragma unroll 8
    for (int k = 0; k < 32; ++k) {
      float4 c = cand[(k << 6) + lane];     // lane-contiguous b128: no conflict
      const int cidx = cbase + (k << 6) + lane;
      #pragma unroll
      for (int j = 0; j < QPW; ++j) {
        float d = fmaf(axv[j], c.x, fmaf(ayv[j], c.y, fmaf(azv[j], c.z, c.w)));
        if (d < best[j]) { best[j] = d; bidx[j] = cidx; }
      }
    }
    __syncthreads();
  }

  // ---- cross-lane argmin: packed (ordered-dist, idx) u64 butterfly ----
  // jnp.argmin tie semantics: lowest distance, then lowest index.
  unsigned long long pk[QPW];
  #pragma unroll
  for (int j = 0; j < QPW; ++j) {
    unsigned u = __float_as_uint(best[j]);
    u ^= (unsigned)((int)u >> 31) | 0x80000000u;   // monotone float->uint
    pk[j] = ((unsigned long long)u << 32) | (unsigned)bidx[j];
  }
  #pragma unroll
  for (int j = 0; j < QPW; ++j) {
    #pragma unroll
    for (int o = 1; o < 64; o <<= 1) {
      unsigned long long other = __shfl_xor(pk[j], o, 64);
      pk[j] = (other < pk[j]) ? other : pk[j];
    }
  }

  // ---- pair sums: lane j<8 of each wave handles its query j ----
  if (lane < QPW) {
    const int j = lane;
    const unsigned idx = (unsigned)(pk[j] & 0xffffffffull);
    float4 b4 = p2aug[idx];
    double ax = qx[j], ay = qy[j], az = qz[j];
    double bx = b4.x, by = b4.y, bz = b4.z;
    double d2 = (ax*ax + ay*ay + az*az) + (bx*bx + by*by + bz*bz)
              - 2.0*(ax*bx + ay*by + az*bz);
    double* pb = pairbuf[(w << 3) + j];
    pb[0]  = sqrt(fmax(d2, 1e-12));
    pb[1]  = ax;    pb[2]  = ay;    pb[3]  = az;
    pb[4]  = bx;    pb[5]  = by;    pb[6]  = bz;
    pb[7]  = ax*bx; pb[8]  = ax*by; pb[9]  = ax*bz;
    pb[10] = ay*bx; pb[11] = ay*by; pb[12] = ay*bz;
    pb[13] = az*bx; pb[14] = az*by; pb[15] = az*bz;
  }
  __syncthreads();

  // ---- 16 column sums -> device atomicAdd; ticket (R2-proven recipe) ----
  if (tid < 16) {
    double s = 0.0;
    #pragma unroll
    for (int i = 0; i < 32; ++i) s += pairbuf[i][tid];
    atomicAdd(acc + tid, s);
  }
  __threadfence();
  __syncthreads();
  if (tid == 0)
    lastFlag = (atomicAdd(&ctl->ticket, 1u) == NB - 1u) ? 1 : 0;
  __syncthreads();
  if (!lastFlag) return;

  // ---- last block: coherent read of totals, solve, compose, emit, reset ----
  if (tid < 16) tot[tid] = atomicAdd(acc + tid, 0.0);   // device-scope RMW read
  __syncthreads();
  if (tid == 0) {
    double s[16];
    #pragma unroll
    for (int i = 0; i < 16; ++i) s[i] = tot[i];
    double R[9], T[3];
    kabsch_solve(s, R, T);
    // compose: pc_new = R*(Rc*p1 + tc) + T = (R*Rc)*p1 + (R*tc + T)
    double Rc[9] = {R0,R1,R2,R3,R4,R5,R6,R7,R8};
    double tc[3] = {T0,T1,T2};
    double Rn[9], tn[3];
    #pragma unroll
    for (int i = 0; i < 3; ++i) {
      #pragma unroll
      for (int j = 0; j < 3; ++j)
        Rn[3*i+j] = R[3*i+0]*Rc[0+j] + R[3*i+1]*Rc[3+j] + R[3*i+2]*Rc[6+j];
      tn[i] = R[3*i+0]*tc[0] + R[3*i+1]*tc[1] + R[3*i+2]*tc[2] + T[i];
    }
    #pragma unroll
    for (int i = 0; i < 9; ++i) ctl->Rc[i] = Rn[i];
    #pragma unroll
    for (int i = 0; i < 3; ++i) ctl->tc[i] = tn[i];
    double errnew = s[0];                   // B == 1
    ctl->done = (fabs(ctl->err - errnew) < ICP_TOL) ? 1 : 0;
    ctl->err  = errnew;
    // out = [Rc | tc] 3x4 (kabsch(p1, Rc*p1+tc) == (Rc,tc) exactly).
    // Written every active iteration; last active write is the answer.
    #pragma unroll
    for (int i = 0; i < 3; ++i) {
      out[4*i + 0] = (float)Rn[3*i + 0];
      out[4*i + 1] = (float)Rn[3*i + 1];
      out[4*i + 2] = (float)Rn[3*i + 2];
      out[4*i + 3] = (float)tn[i];
    }
    // reset for next dispatch (visible at kernel boundary)
    #pragma unroll
    for (int i = 0; i < 16; ++i) acc[i] = 0.0;
    ctl->ticket = 0u;
  }
}

// ---------------------------------------------------------------------------
extern "C" void kernel_launch(void* const* d_in, const int* in_sizes, int n_in,
                              void* d_out, int out_size, void* d_ws, size_t ws_size,
                              hipStream_t stream) {
  const float* p1 = (const float*)d_in[0];
  const float* p2 = (const float*)d_in[1];
  float* out = (float*)d_out;

  char* ws = (char*)d_ws;
  float4* p2aug = (float4*)ws;                       // 128 KiB
  IcpCtl* ctl   = (IcpCtl*)(ws + 128*1024);          // ~120 B
  double* acc   = (double*)(ws + 128*1024 + 512);    // 128 B

  icp_prep<<<N_PTS/256, 256, 0, stream>>>(p2, p2aug, ctl, acc);
  for (int it = 0; it < ICP_STEPS; ++it)
    icp_iter<<<NB, 256, 0, stream>>>(p1, p2aug, ctl, acc, out);
}

// Round 6
// 961.380 us; speedup vs baseline: 1.5867x; 1.0972x over previous
//
#include <hip/hip_runtime.h>
#include <math.h>

#define N_PTS 8192
#define ICP_STEPS 21      // STEPLIM + 1 scan iterations
#define ICP_TOL 1e-4

#define NB 256            // one block per CU; block owns 32 queries
#define QPW 8             // queries per wave (lane-sliced candidates)
#define CHUNK 2048        // candidates staged in LDS per chunk (32 KiB)
#define NCHUNK 4          // 4 * 2048 = 8192

struct IcpCtl {
  double err;
  double Rc[9];     // cumulative rotation (row-major): pc = Rc*p1 + tc
  double tc[3];
  int done;
  unsigned ticket;  // reduce-completion ticket (selects solver block)
};

// ---------------------------------------------------------------------------
// prep: p2aug = (x,y,z,|b|^2) float4; ctl reset (runs every replay)
// ---------------------------------------------------------------------------
__global__ __launch_bounds__(256) void icp_prep(const float* __restrict__ p2,
                                                float4* __restrict__ p2aug,
                                                IcpCtl* __restrict__ ctl) {
  int t = blockIdx.x * 256 + threadIdx.x;   // grid covers exactly N_PTS
  float x = p2[3*t], y = p2[3*t+1], z = p2[3*t+2];
  p2aug[t] = make_float4(x, y, z, fmaf(x, x, fmaf(y, y, z*z)));
  if (t == 0) {
    ctl->err = 0.0; ctl->done = 0; ctl->ticket = 0u;
    #pragma unroll
    for (int i = 0; i < 9; ++i) ctl->Rc[i] = (i % 4 == 0) ? 1.0 : 0.0;
    ctl->tc[0] = ctl->tc[1] = ctl->tc[2] = 0.0;
  }
}

// ---------------------------------------------------------------------------
// Register-only 3x3 Kabsch from raw sums. s[0]=sum dmin, s[1..3]=sum src,
// s[4..6]=sum dst, s[7..15]=sum src_i*dst_j (row-major). No runtime-indexed
// arrays -> no scratch. Hard-coded Jacobi pairs, 6 sweeps.
// R = V diag(1,1,detV) U~^T (right-handed U~) == reference's sign-fixed SVD.
// ---------------------------------------------------------------------------
__device__ __forceinline__ void kabsch_solve(const double* s, double* R, double* T) {
  const double n = (double)N_PTS;
  const double c1x = s[1]/n, c1y = s[2]/n, c1z = s[3]/n;
  const double c2x = s[4]/n, c2y = s[5]/n, c2z = s[6]/n;
  const double h00 = s[7]  - n*c1x*c2x, h01 = s[8]  - n*c1x*c2y, h02 = s[9]  - n*c1x*c2z;
  const double h10 = s[10] - n*c1y*c2x, h11 = s[11] - n*c1y*c2y, h12 = s[12] - n*c1y*c2z;
  const double h20 = s[13] - n*c1z*c2x, h21 = s[14] - n*c1z*c2y, h22 = s[15] - n*c1z*c2z;

  // A = H^T H (symmetric): a_ij = col_i(H) . col_j(H)
  double a00 = h00*h00 + h10*h10 + h20*h20;
  double a01 = h00*h01 + h10*h11 + h20*h21;
  double a02 = h00*h02 + h10*h12 + h20*h22;
  double a11 = h01*h01 + h11*h11 + h21*h21;
  double a12 = h01*h02 + h11*h12 + h21*h22;
  double a22 = h02*h02 + h12*h12 + h22*h22;

  double v00=1.0, v01=0.0, v02=0.0;   // columns of V are eigenvectors
  double v10=0.0, v11=1.0, v12=0.0;
  double v20=0.0, v21=0.0, v22=1.0;

#define ROT3(app, aqq, apq, arp, arq, vpa, vqa, vpb, vqb, vpc, vqc)              \
  {                                                                              \
    double apq_ = apq;                                                           \
    if (fabs(apq_) > 1e-300) {                                                   \
      double tau = (aqq - app) / (2.0 * apq_);                                   \
      double tt  = (tau >= 0.0 ? 1.0 : -1.0) / (fabs(tau) + sqrt(1.0 + tau*tau));\
      double c_  = 1.0 / sqrt(1.0 + tt*tt), sn = tt * c_;                        \
      app -= tt * apq_;  aqq += tt * apq_;  apq = 0.0;                           \
      double t1 = arp, t2 = arq;                                                 \
      arp = c_*t1 - sn*t2;  arq = sn*t1 + c_*t2;                                 \
      t1 = vpa; t2 = vqa; vpa = c_*t1 - sn*t2; vqa = sn*t1 + c_*t2;              \
      t1 = vpb; t2 = vqb; vpb = c_*t1 - sn*t2; vqb = sn*t1 + c_*t2;              \
      t1 = vpc; t2 = vqc; vpc = c_*t1 - sn*t2; vqc = sn*t1 + c_*t2;              \
    }                                                                            \
  }

  #pragma unroll
  for (int sweep = 0; sweep < 6; ++sweep) {
    ROT3(a00, a11, a01, a02, a12, v00, v01, v10, v11, v20, v21);  // (0,1) r=2
    ROT3(a00, a22, a02, a01, a12, v00, v02, v10, v12, v20, v22);  // (0,2) r=1
    ROT3(a11, a22, a12, a01, a02, v01, v02, v11, v12, v21, v22);  // (1,2) r=0
  }
#undef ROT3

  // sort eigenpairs descending (columns as named triples)
  double l0 = a00, l1 = a11, l2 = a22;
  double e0x=v00, e0y=v10, e0z=v20;
  double e1x=v01, e1y=v11, e1z=v21;
  double e2x=v02, e2y=v12, e2z=v22;
#define CSWAP(la, lb, xa, ya, za, xb, yb, zb)                                    \
  if (lb > la) { double t_;                                                      \
    t_ = la; la = lb; lb = t_;  t_ = xa; xa = xb; xb = t_;                       \
    t_ = ya; ya = yb; yb = t_;  t_ = za; za = zb; zb = t_; }
  CSWAP(l0, l1, e0x, e0y, e0z, e1x, e1y, e1z);
  CSWAP(l0, l2, e0x, e0y, e0z, e2x, e2y, e2z);
  CSWAP(l1, l2, e1x, e1y, e1z, e2x, e2y, e2z);
#undef CSWAP

  double detV = e0x*(e1y*e2z - e1z*e2y) - e0y*(e1x*e2z - e1z*e2x)
              + e0z*(e1x*e2y - e1y*e2x);
  const double dsg = (detV >= 0.0) ? 1.0 : -1.0;

  // U~ columns: u0 = H e0 / |.|, u1 = orth(H e1), u2 = u0 x u1
  double u0x = h00*e0x + h01*e0y + h02*e0z;
  double u0y = h10*e0x + h11*e0y + h12*e0z;
  double u0z = h20*e0x + h21*e0y + h22*e0z;
  double n0 = sqrt(u0x*u0x + u0y*u0y + u0z*u0z);
  if (!(n0 > 1e-150)) {
    R[0]=1.0; R[1]=0.0; R[2]=0.0; R[3]=0.0; R[4]=1.0; R[5]=0.0;
    R[6]=0.0; R[7]=0.0; R[8]=1.0;
    T[0]=c2x-c1x; T[1]=c2y-c1y; T[2]=c2z-c1z;
    return;
  }
  u0x /= n0; u0y /= n0; u0z /= n0;
  double u1x = h00*e1x + h01*e1y + h02*e1z;
  double u1y = h10*e1x + h11*e1y + h12*e1z;
  double u1z = h20*e1x + h21*e1y + h22*e1z;
  const double d10 = u1x*u0x + u1y*u0y + u1z*u0z;
  u1x -= d10*u0x; u1y -= d10*u0y; u1z -= d10*u0z;
  double n1 = sqrt(u1x*u1x + u1y*u1y + u1z*u1z);
  if (!(n1 > 1e-150)) {
    R[0]=1.0; R[1]=0.0; R[2]=0.0; R[3]=0.0; R[4]=1.0; R[5]=0.0;
    R[6]=0.0; R[7]=0.0; R[8]=1.0;
    T[0]=c2x-c1x; T[1]=c2y-c1y; T[2]=c2z-c1z;
    return;
  }
  u1x /= n1; u1y /= n1; u1z /= n1;
  const double u2x = u0y*u1z - u0z*u1y;
  const double u2y = u0z*u1x - u0x*u1z;
  const double u2z = u0x*u1y - u0y*u1x;

  // R[i][j] = e0_i u0_j + e1_i u1_j + dsg e2_i u2_j
  R[0] = e0x*u0x + e1x*u1x + dsg*e2x*u2x;
  R[1] = e0x*u0y + e1x*u1y + dsg*e2x*u2y;
  R[2] = e0x*u0z + e1x*u1z + dsg*e2x*u2z;
  R[3] = e0y*u0x + e1y*u1x + dsg*e2y*u2x;
  R[4] = e0y*u0y + e1y*u1y + dsg*e2y*u2y;
  R[5] = e0y*u0z + e1y*u1z + dsg*e2y*u2z;
  R[6] = e0z*u0x + e1z*u1x + dsg*e2z*u2x;
  R[7] = e0z*u0y + e1z*u1y + dsg*e2z*u2y;
  R[8] = e0z*u0z + e1z*u1z + dsg*e2z*u2z;
  T[0] = c2x - (R[0]*c1x + R[1]*c1y + R[2]*c1z);
  T[1] = c2y - (R[3]*c1x + R[4]*c1y + R[5]*c1z);
  T[2] = c2z - (R[6]*c1x + R[7]*c1y + R[8]*c1z);
}

// 16-value double block reduction (256 threads = 4 waves); result in tot[16]
__device__ __forceinline__ void block_reduce16(double* v, double* tot, double* lds) {
  const int lane = threadIdx.x & 63;
  const int w    = threadIdx.x >> 6;
  #pragma unroll
  for (int q = 0; q < 16; ++q) {
    double x = v[q];
    for (int o = 32; o > 0; o >>= 1) x += __shfl_down(x, o, 64);
    if (lane == 0) lds[w*16 + q] = x;
  }
  __syncthreads();
  if (threadIdx.x < 16)
    tot[threadIdx.x] = lds[threadIdx.x] + lds[16 + threadIdx.x]
                     + lds[32 + threadIdx.x] + lds[48 + threadIdx.x];
  __syncthreads();
}

// ---------------------------------------------------------------------------
// One fused ICP iteration (one dispatch):
//   NN full scan (wave owns 8 queries, 64 lanes = candidate slices, LDS
//   chunks, 8-way ILP) -> shfl_xor u64 butterfly argmin -> block pair sums
//   (padded LDS) -> 16 plain stores to part[bid] (NO shared atomics) ->
//   ACQ_REL ticket -> last block: tree-reduce 256 rows, register Kabsch,
//   compose cumulative transform, done-logic, write out, reset ticket.
// ---------------------------------------------------------------------------
__global__ __launch_bounds__(256) void icp_iter(const float* __restrict__ p1,
                                                const float4* __restrict__ p2aug,
                                                IcpCtl* __restrict__ ctl,
                                                double* __restrict__ part,
                                                float* __restrict__ out) {
  if (ctl->done) return;                    // uniform across grid
  __shared__ float4 cand[CHUNK];            // 32 KiB
  __shared__ double pairbuf[32][17];        // +1 pad: conflict-free columns
  __shared__ double tot[16];
  __shared__ double lds[64];
  __shared__ int lastFlag;

  const int tid  = threadIdx.x;
  const int lane = tid & 63;
  const int w    = tid >> 6;

  const double R0 = ctl->Rc[0], R1 = ctl->Rc[1], R2 = ctl->Rc[2];
  const double R3 = ctl->Rc[3], R4 = ctl->Rc[4], R5 = ctl->Rc[5];
  const double R6 = ctl->Rc[6], R7 = ctl->Rc[7], R8 = ctl->Rc[8];
  const double T0 = ctl->tc[0], T1 = ctl->tc[1], T2 = ctl->tc[2];

  // ---- wave w owns queries qbase..qbase+7 (uniform across its lanes) ----
  const int qbase = (blockIdx.x << 5) + (w << 3);
  float qx[QPW], qy[QPW], qz[QPW], axv[QPW], ayv[QPW], azv[QPW], best[QPW];
  int bidx[QPW];
  #pragma unroll
  for (int j = 0; j < QPW; ++j) {
    const int q = qbase + j;
    const double X = (double)p1[3*q], Y = (double)p1[3*q+1], Z = (double)p1[3*q+2];
    qx[j] = (float)(R0*X + R1*Y + R2*Z + T0);   // fp32-rounded, matches ref pc
    qy[j] = (float)(R3*X + R4*Y + R5*Z + T1);
    qz[j] = (float)(R6*X + R7*Y + R8*Z + T2);
    axv[j] = -2.f*qx[j]; ayv[j] = -2.f*qy[j]; azv[j] = -2.f*qz[j];
    best[j] = __builtin_inff(); bidx[j] = 0;
  }

  // ---- NN scan: 4 chunks of 2048 candidates, reg-prefetch next chunk ----
  float4 pf[8];
  #pragma unroll
  for (int k = 0; k < 8; ++k) pf[k] = p2aug[(k << 8) + tid];
  for (int cb = 0; cb < NCHUNK; ++cb) {
    #pragma unroll
    for (int k = 0; k < 8; ++k) cand[(k << 8) + tid] = pf[k];
    __syncthreads();
    if (cb + 1 < NCHUNK) {
      #pragma unroll
      for (int k = 0; k < 8; ++k)
        pf[k] = p2aug[((cb + 1) << 11) + (k << 8) + tid];
    }
    const int cbase = cb << 11;
    #pragma unroll 8
    for (int k = 0; k < 32; ++k) {
      float4 c = cand[(k << 6) + lane];     // lane-contiguous b128: no conflict
      const int cidx = cbase + (k << 6) + lane;
      #pragma unroll
      for (int j = 0; j < QPW; ++j) {
        float d = fmaf(axv[j], c.x, fmaf(ayv[j], c.y, fmaf(azv[j], c.z, c.w)));
        if (d < best[j]) { best[j] = d; bidx[j] = cidx; }
      }
    }
    __syncthreads();
  }

  // ---- cross-lane argmin: packed (ordered-dist, idx) u64 butterfly ----
  // jnp.argmin tie semantics: lowest distance, then lowest index.
  unsigned long long pk[QPW];
  #pragma unroll
  for (int j = 0; j < QPW; ++j) {
    unsigned u = __float_as_uint(best[j]);
    u ^= (unsigned)((int)u >> 31) | 0x80000000u;   // monotone float->uint
    pk[j] = ((unsigned long long)u << 32) | (unsigned)bidx[j];
  }
  #pragma unroll
  for (int j = 0; j < QPW; ++j) {
    #pragma unroll
    for (int o = 1; o < 64; o <<= 1) {
      unsigned long long other = __shfl_xor(pk[j], o, 64);
      pk[j] = (other < pk[j]) ? other : pk[j];
    }
  }

  // ---- pair sums: lane j<8 of each wave handles its query j ----
  if (lane < QPW) {
    const int j = lane;
    const unsigned idx = (unsigned)(pk[j] & 0xffffffffull);
    float4 b4 = p2aug[idx];
    double ax = qx[j], ay = qy[j], az = qz[j];
    double bx = b4.x, by = b4.y, bz = b4.z;
    double d2 = (ax*ax + ay*ay + az*az) + (bx*bx + by*by + bz*bz)
              - 2.0*(ax*bx + ay*by + az*bz);
    double* pb = pairbuf[(w << 3) + j];
    pb[0]  = sqrt(fmax(d2, 1e-12));
    pb[1]  = ax;    pb[2]  = ay;    pb[3]  = az;
    pb[4]  = bx;    pb[5]  = by;    pb[6]  = bz;
    pb[7]  = ax*bx; pb[8]  = ax*by; pb[9]  = ax*bz;
    pb[10] = ay*bx; pb[11] = ay*by; pb[12] = ay*bz;
    pb[13] = az*bx; pb[14] = az*by; pb[15] = az*bz;
  }
  __syncthreads();

  // ---- 16 column sums -> PLAIN stores to this block's private row ----
  if (tid < 16) {
    double s = 0.0;
    #pragma unroll
    for (int i = 0; i < 32; ++i) s += pairbuf[i][tid];
    part[(blockIdx.x << 4) + tid] = s;      // no contention, no RMW
  }
  __syncthreads();
  if (tid == 0) {
    // ACQ_REL at agent scope: releases this block's row (wbl2 before RMW),
    // acquires all prior rows for the winning (last) block (inv after RMW).
    unsigned old = __hip_atomic_fetch_add(&ctl->ticket, 1u,
                      __ATOMIC_ACQ_REL, __HIP_MEMORY_SCOPE_AGENT);
    lastFlag = (old == NB - 1u) ? 1 : 0;
  }
  __syncthreads();
  if (!lastFlag) return;

  // ---- last block: tree-reduce the 256 partial rows (1 row per thread) ----
  double v[16];
  {
    const double* row = part + (tid << 4);
    #pragma unroll
    for (int c = 0; c < 16; ++c) v[c] = row[c];
  }
  block_reduce16(v, tot, lds);

  if (tid == 0) {
    double s[16];
    #pragma unroll
    for (int i = 0; i < 16; ++i) s[i] = tot[i];
    double R[9], T[3];
    kabsch_solve(s, R, T);
    // compose: pc_new = R*(Rc*p1 + tc) + T = (R*Rc)*p1 + (R*tc + T)
    double Rc[9] = {R0,R1,R2,R3,R4,R5,R6,R7,R8};
    double tc[3] = {T0,T1,T2};
    double Rn[9], tn[3];
    #pragma unroll
    for (int i = 0; i < 3; ++i) {
      #pragma unroll
      for (int j = 0; j < 3; ++j)
        Rn[3*i+j] = R[3*i+0]*Rc[0+j] + R[3*i+1]*Rc[3+j] + R[3*i+2]*Rc[6+j];
      tn[i] = R[3*i+0]*tc[0] + R[3*i+1]*tc[1] + R[3*i+2]*tc[2] + T[i];
    }
    #pragma unroll
    for (int i = 0; i < 9; ++i) ctl->Rc[i] = Rn[i];
    #pragma unroll
    for (int i = 0; i < 3; ++i) ctl->tc[i] = tn[i];
    double errnew = s[0];                   // B == 1
    ctl->done = (fabs(ctl->err - errnew) < ICP_TOL) ? 1 : 0;
    ctl->err  = errnew;
    // out = [Rc | tc] 3x4 (kabsch(p1, Rc*p1+tc) == (Rc,tc) exactly).
    #pragma unroll
    for (int i = 0; i < 3; ++i) {
      out[4*i + 0] = (float)Rn[3*i + 0];
      out[4*i + 1] = (float)Rn[3*i + 1];
      out[4*i + 2] = (float)Rn[3*i + 2];
      out[4*i + 3] = (float)tn[i];
    }
    ctl->ticket = 0u;   // reset; visible at next kernel boundary
  }
}

// ---------------------------------------------------------------------------
extern "C" void kernel_launch(void* const* d_in, const int* in_sizes, int n_in,
                              void* d_out, int out_size, void* d_ws, size_t ws_size,
                              hipStream_t stream) {
  const float* p1 = (const float*)d_in[0];
  const float* p2 = (const float*)d_in[1];
  float* out = (float*)d_out;

  char* ws = (char*)d_ws;
  float4* p2aug = (float4*)ws;                       // 128 KiB
  IcpCtl* ctl   = (IcpCtl*)(ws + 128*1024);          // ~120 B
  double* part  = (double*)(ws + 128*1024 + 512);    // 32 KiB (256 x 16 f64)

  icp_prep<<<N_PTS/256, 256, 0, stream>>>(p2, p2aug, ctl);
  for (int it = 0; it < ICP_STEPS; ++it)
    icp_iter<<<NB, 256, 0, stream>>>(p1, p2aug, ctl, part, out);
}

// Round 7
// 842.611 us; speedup vs baseline: 1.8104x; 1.1410x over previous
//
#include <hip/hip_runtime.h>
#include <math.h>

#define N_PTS 8192
#define ICP_STEPS 21      // STEPLIM + 1 scan iterations
#define ICP_TOL 1e-4

#define NB 256            // one block per CU; block owns 32 queries
#define QPW 8             // queries per wave (lane-sliced candidates)
#define CHUNK 2048        // candidates staged in LDS per chunk (32 KiB)
#define NCHUNK 4          // 4 * 2048 = 8192

struct IcpCtl {
  double err;
  double Rc[9];     // cumulative rotation (row-major): pc = Rc*p1 + tc
  double tc[3];
  int done;
  unsigned ticket;  // reduce-completion ticket (selects solver block)
};

// ---------------------------------------------------------------------------
// prep: p2aug = (x,y,z,|b|^2) float4; ctl/acc reset (runs every replay)
// ---------------------------------------------------------------------------
__global__ __launch_bounds__(256) void icp_prep(const float* __restrict__ p2,
                                                float4* __restrict__ p2aug,
                                                IcpCtl* __restrict__ ctl,
                                                double* __restrict__ acc) {
  int t = blockIdx.x * 256 + threadIdx.x;   // grid covers exactly N_PTS
  float x = p2[3*t], y = p2[3*t+1], z = p2[3*t+2];
  p2aug[t] = make_float4(x, y, z, fmaf(x, x, fmaf(y, y, z*z)));
  if (t == 0) {
    ctl->err = 0.0; ctl->done = 0; ctl->ticket = 0u;
    #pragma unroll
    for (int i = 0; i < 9; ++i) ctl->Rc[i] = (i % 4 == 0) ? 1.0 : 0.0;
    ctl->tc[0] = ctl->tc[1] = ctl->tc[2] = 0.0;
    #pragma unroll
    for (int i = 0; i < 16; ++i) acc[i] = 0.0;
  }
}

// ---------------------------------------------------------------------------
// Register-only 3x3 Kabsch from raw sums (no runtime-indexed arrays -> no
// scratch). s[0]=sum dmin, s[1..3]=sum src, s[4..6]=sum dst, s[7..15]=sum
// src_i*dst_j. R = V diag(1,1,detV) U~^T == reference's sign-fixed SVD.
// ---------------------------------------------------------------------------
__device__ __forceinline__ void kabsch_solve(const double* s, double* R, double* T) {
  const double n = (double)N_PTS;
  const double c1x = s[1]/n, c1y = s[2]/n, c1z = s[3]/n;
  const double c2x = s[4]/n, c2y = s[5]/n, c2z = s[6]/n;
  const double h00 = s[7]  - n*c1x*c2x, h01 = s[8]  - n*c1x*c2y, h02 = s[9]  - n*c1x*c2z;
  const double h10 = s[10] - n*c1y*c2x, h11 = s[11] - n*c1y*c2y, h12 = s[12] - n*c1y*c2z;
  const double h20 = s[13] - n*c1z*c2x, h21 = s[14] - n*c1z*c2y, h22 = s[15] - n*c1z*c2z;

  double a00 = h00*h00 + h10*h10 + h20*h20;
  double a01 = h00*h01 + h10*h11 + h20*h21;
  double a02 = h00*h02 + h10*h12 + h20*h22;
  double a11 = h01*h01 + h11*h11 + h21*h21;
  double a12 = h01*h02 + h11*h12 + h21*h22;
  double a22 = h02*h02 + h12*h12 + h22*h22;

  double v00=1.0, v01=0.0, v02=0.0;
  double v10=0.0, v11=1.0, v12=0.0;
  double v20=0.0, v21=0.0, v22=1.0;

#define ROT3(app, aqq, apq, arp, arq, vpa, vqa, vpb, vqb, vpc, vqc)              \
  {                                                                              \
    double apq_ = apq;                                                           \
    if (fabs(apq_) > 1e-300) {                                                   \
      double tau = (aqq - app) / (2.0 * apq_);                                   \
      double tt  = (tau >= 0.0 ? 1.0 : -1.0) / (fabs(tau) + sqrt(1.0 + tau*tau));\
      double c_  = 1.0 / sqrt(1.0 + tt*tt), sn = tt * c_;                        \
      app -= tt * apq_;  aqq += tt * apq_;  apq = 0.0;                           \
      double t1 = arp, t2 = arq;                                                 \
      arp = c_*t1 - sn*t2;  arq = sn*t1 + c_*t2;                                 \
      t1 = vpa; t2 = vqa; vpa = c_*t1 - sn*t2; vqa = sn*t1 + c_*t2;              \
      t1 = vpb; t2 = vqb; vpb = c_*t1 - sn*t2; vqb = sn*t1 + c_*t2;              \
      t1 = vpc; t2 = vqc; vpc = c_*t1 - sn*t2; vqc = sn*t1 + c_*t2;              \
    }                                                                            \
  }

  #pragma unroll
  for (int sweep = 0; sweep < 6; ++sweep) {
    ROT3(a00, a11, a01, a02, a12, v00, v01, v10, v11, v20, v21);  // (0,1)
    ROT3(a00, a22, a02, a01, a12, v00, v02, v10, v12, v20, v22);  // (0,2)
    ROT3(a11, a22, a12, a01, a02, v01, v02, v11, v12, v21, v22);  // (1,2)
  }
#undef ROT3

  double l0 = a00, l1 = a11, l2 = a22;
  double e0x=v00, e0y=v10, e0z=v20;
  double e1x=v01, e1y=v11, e1z=v21;
  double e2x=v02, e2y=v12, e2z=v22;
#define CSWAP(la, lb, xa, ya, za, xb, yb, zb)                                    \
  if (lb > la) { double t_;                                                      \
    t_ = la; la = lb; lb = t_;  t_ = xa; xa = xb; xb = t_;                       \
    t_ = ya; ya = yb; yb = t_;  t_ = za; za = zb; zb = t_; }
  CSWAP(l0, l1, e0x, e0y, e0z, e1x, e1y, e1z);
  CSWAP(l0, l2, e0x, e0y, e0z, e2x, e2y, e2z);
  CSWAP(l1, l2, e1x, e1y, e1z, e2x, e2y, e2z);
#undef CSWAP

  double detV = e0x*(e1y*e2z - e1z*e2y) - e0y*(e1x*e2z - e1z*e2x)
              + e0z*(e1x*e2y - e1y*e2x);
  const double dsg = (detV >= 0.0) ? 1.0 : -1.0;

  double u0x = h00*e0x + h01*e0y + h02*e0z;
  double u0y = h10*e0x + h11*e0y + h12*e0z;
  double u0z = h20*e0x + h21*e0y + h22*e0z;
  double n0 = sqrt(u0x*u0x + u0y*u0y + u0z*u0z);
  if (!(n0 > 1e-150)) {
    R[0]=1.0; R[1]=0.0; R[2]=0.0; R[3]=0.0; R[4]=1.0; R[5]=0.0;
    R[6]=0.0; R[7]=0.0; R[8]=1.0;
    T[0]=c2x-c1x; T[1]=c2y-c1y; T[2]=c2z-c1z;
    return;
  }
  u0x /= n0; u0y /= n0; u0z /= n0;
  double u1x = h00*e1x + h01*e1y + h02*e1z;
  double u1y = h10*e1x + h11*e1y + h12*e1z;
  double u1z = h20*e1x + h21*e1y + h22*e1z;
  const double d10 = u1x*u0x + u1y*u0y + u1z*u0z;
  u1x -= d10*u0x; u1y -= d10*u0y; u1z -= d10*u0z;
  double n1 = sqrt(u1x*u1x + u1y*u1y + u1z*u1z);
  if (!(n1 > 1e-150)) {
    R[0]=1.0; R[1]=0.0; R[2]=0.0; R[3]=0.0; R[4]=1.0; R[5]=0.0;
    R[6]=0.0; R[7]=0.0; R[8]=1.0;
    T[0]=c2x-c1x; T[1]=c2y-c1y; T[2]=c2z-c1z;
    return;
  }
  u1x /= n1; u1y /= n1; u1z /= n1;
  const double u2x = u0y*u1z - u0z*u1y;
  const double u2y = u0z*u1x - u0x*u1z;
  const double u2z = u0x*u1y - u0y*u1x;

  R[0] = e0x*u0x + e1x*u1x + dsg*e2x*u2x;
  R[1] = e0x*u0y + e1x*u1y + dsg*e2x*u2y;
  R[2] = e0x*u0z + e1x*u1z + dsg*e2x*u2z;
  R[3] = e0y*u0x + e1y*u1x + dsg*e2y*u2x;
  R[4] = e0y*u0y + e1y*u1y + dsg*e2y*u2y;
  R[5] = e0y*u0z + e1y*u1z + dsg*e2y*u2z;
  R[6] = e0z*u0x + e1z*u1x + dsg*e2z*u2x;
  R[7] = e0z*u0y + e1z*u1y + dsg*e2z*u2y;
  R[8] = e0z*u0z + e1z*u1z + dsg*e2z*u2z;
  T[0] = c2x - (R[0]*c1x + R[1]*c1y + R[2]*c1z);
  T[1] = c2y - (R[3]*c1x + R[4]*c1y + R[5]*c1z);
  T[2] = c2z - (R[6]*c1x + R[7]*c1y + R[8]*c1z);
}

// ---------------------------------------------------------------------------
// One fused ICP iteration (one dispatch). NO release/acquire fences anywhere:
// block sums go to memory-side RELAXED f64 atomicAdds (cheap, R2-proven);
// adds->ticket ordering is a raw in-wave `s_waitcnt vmcnt(0)` (a wait, not a
// cache flush); last block reads totals via relaxed RMW; cross-dispatch
// visibility of ctl/acc resets comes from the implicit end-of-kernel release.
// ---------------------------------------------------------------------------
__global__ __launch_bounds__(256) void icp_iter(const float* __restrict__ p1,
                                                const float4* __restrict__ p2aug,
                                                IcpCtl* __restrict__ ctl,
                                                double* __restrict__ acc,
                                                float* __restrict__ out) {
  if (ctl->done) return;                    // uniform across grid
  __shared__ float4 cand[CHUNK];            // 32 KiB
  __shared__ double pairbuf[32][17];        // +1 pad: conflict-free columns
  __shared__ double tot[16];
  __shared__ int lastFlag;

  const int tid  = threadIdx.x;
  const int lane = tid & 63;
  const int w    = tid >> 6;

  const double R0 = ctl->Rc[0], R1 = ctl->Rc[1], R2 = ctl->Rc[2];
  const double R3 = ctl->Rc[3], R4 = ctl->Rc[4], R5 = ctl->Rc[5];
  const double R6 = ctl->Rc[6], R7 = ctl->Rc[7], R8 = ctl->Rc[8];
  const double T0 = ctl->tc[0], T1 = ctl->tc[1], T2 = ctl->tc[2];

  // ---- wave w owns queries qbase..qbase+7 (uniform across its lanes) ----
  const int qbase = (blockIdx.x << 5) + (w << 3);
  float qx[QPW], qy[QPW], qz[QPW], axv[QPW], ayv[QPW], azv[QPW], best[QPW];
  int bidx[QPW];
  #pragma unroll
  for (int j = 0; j < QPW; ++j) {
    const int q = qbase + j;
    const double X = (double)p1[3*q], Y = (double)p1[3*q+1], Z = (double)p1[3*q+2];
    qx[j] = (float)(R0*X + R1*Y + R2*Z + T0);   // fp32-rounded, matches ref pc
    qy[j] = (float)(R3*X + R4*Y + R5*Z + T1);
    qz[j] = (float)(R6*X + R7*Y + R8*Z + T2);
    axv[j] = -2.f*qx[j]; ayv[j] = -2.f*qy[j]; azv[j] = -2.f*qz[j];
    best[j] = __builtin_inff(); bidx[j] = 0;
  }

  // ---- NN scan: 4 chunks of 2048 candidates, reg-prefetch next chunk ----
  float4 pf[8];
  #pragma unroll
  for (int k = 0; k < 8; ++k) pf[k] = p2aug[(k << 8) + tid];
  for (int cb = 0; cb < NCHUNK; ++cb) {
    #pragma unroll
    for (int k = 0; k < 8; ++k) cand[(k << 8) + tid] = pf[k];
    __syncthreads();
    if (cb + 1 < NCHUNK) {
      #pragma unroll
      for (int k = 0; k < 8; ++k)
        pf[k] = p2aug[((cb + 1) << 11) + (k << 8) + tid];
    }
    const int cbase = cb << 11;
    #pragma unroll 8
    for (int k = 0; k < 32; ++k) {
      float4 c = cand[(k << 6) + lane];     // lane-contiguous b128: no conflict
      const int cidx = cbase + (k << 6) + lane;
      #pragma unroll
      for (int j = 0; j < QPW; ++j) {
        float d = fmaf(axv[j], c.x, fmaf(ayv[j], c.y, fmaf(azv[j], c.z, c.w)));
        if (d < best[j]) { best[j] = d; bidx[j] = cidx; }
      }
    }
    __syncthreads();
  }

  // ---- cross-lane argmin: packed (ordered-dist, idx) u64 butterfly ----
  // jnp.argmin tie semantics: lowest distance, then lowest index.
  unsigned long long pk[QPW];
  #pragma unroll
  for (int j = 0; j < QPW; ++j) {
    unsigned u = __float_as_uint(best[j]);
    u ^= (unsigned)((int)u >> 31) | 0x80000000u;   // monotone float->uint
    pk[j] = ((unsigned long long)u << 32) | (unsigned)bidx[j];
  }
  #pragma unroll
  for (int j = 0; j < QPW; ++j) {
    #pragma unroll
    for (int o = 1; o < 64; o <<= 1) {
      unsigned long long other = __shfl_xor(pk[j], o, 64);
      pk[j] = (other < pk[j]) ? other : pk[j];
    }
  }

  // ---- pair sums: lane j<8 of each wave handles its query j ----
  if (lane < QPW) {
    const int j = lane;
    const unsigned idx = (unsigned)(pk[j] & 0xffffffffull);
    float4 b4 = p2aug[idx];
    double ax = qx[j], ay = qy[j], az = qz[j];
    double bx = b4.x, by = b4.y, bz = b4.z;
    double d2 = (ax*ax + ay*ay + az*az) + (bx*bx + by*by + bz*bz)
              - 2.0*(ax*bx + ay*by + az*bz);
    double* pb = pairbuf[(w << 3) + j];
    pb[0]  = sqrt(fmax(d2, 1e-12));
    pb[1]  = ax;    pb[2]  = ay;    pb[3]  = az;
    pb[4]  = bx;    pb[5]  = by;    pb[6]  = bz;
    pb[7]  = ax*bx; pb[8]  = ax*by; pb[9]  = ax*bz;
    pb[10] = ay*bx; pb[11] = ay*by; pb[12] = ay*bz;
    pb[13] = az*bx; pb[14] = az*by; pb[15] = az*bz;
  }
  __syncthreads();

  // ---- 16 column sums -> RELAXED memory-side atomicAdd (no fence) ----
  if (tid < 16) {
    double s = 0.0;
    #pragma unroll
    for (int i = 0; i < 32; ++i) s += pairbuf[i][tid];
    atomicAdd(acc + tid, s);                // device-scope, relaxed, memory-side
  }
  if (tid == 0) {
    // Same wave (lanes 0-15) issued the adds; vmcnt is per-wave, so this
    // waits for their completion at the coherence point. A WAIT, not a flush.
    asm volatile("s_waitcnt vmcnt(0)" ::: "memory");
    unsigned old = __hip_atomic_fetch_add(&ctl->ticket, 1u,
                      __ATOMIC_RELAXED, __HIP_MEMORY_SCOPE_AGENT);
    lastFlag = (old == NB - 1u) ? 1 : 0;
  }
  __syncthreads();
  if (!lastFlag) return;

  // ---- last block: totals via relaxed RMW read (memory-side, R2-proven) ----
  if (tid < 16) tot[tid] = atomicAdd(acc + tid, 0.0);
  __syncthreads();
  if (tid == 0) {
    double s[16];
    #pragma unroll
    for (int i = 0; i < 16; ++i) s[i] = tot[i];
    double R[9], T[3];
    kabsch_solve(s, R, T);
    // compose: pc_new = R*(Rc*p1 + tc) + T = (R*Rc)*p1 + (R*tc + T)
    double Rc[9] = {R0,R1,R2,R3,R4,R5,R6,R7,R8};
    double tc[3] = {T0,T1,T2};
    double Rn[9], tn[3];
    #pragma unroll
    for (int i = 0; i < 3; ++i) {
      #pragma unroll
      for (int j = 0; j < 3; ++j)
        Rn[3*i+j] = R[3*i+0]*Rc[0+j] + R[3*i+1]*Rc[3+j] + R[3*i+2]*Rc[6+j];
      tn[i] = R[3*i+0]*tc[0] + R[3*i+1]*tc[1] + R[3*i+2]*tc[2] + T[i];
    }
    #pragma unroll
    for (int i = 0; i < 9; ++i) ctl->Rc[i] = Rn[i];
    #pragma unroll
    for (int i = 0; i < 3; ++i) ctl->tc[i] = tn[i];
    double errnew = s[0];                   // B == 1
    ctl->done = (fabs(ctl->err - errnew) < ICP_TOL) ? 1 : 0;
    ctl->err  = errnew;
    // out = [Rc | tc] 3x4 (kabsch(p1, Rc*p1+tc) == (Rc,tc) exactly).
    #pragma unroll
    for (int i = 0; i < 3; ++i) {
      out[4*i + 0] = (float)Rn[3*i + 0];
      out[4*i + 1] = (float)Rn[3*i + 1];
      out[4*i + 2] = (float)Rn[3*i + 2];
      out[4*i + 3] = (float)tn[i];
    }
    // reset for next dispatch; end-of-kernel release makes these visible
    #pragma unroll
    for (int i = 0; i < 16; ++i) acc[i] = 0.0;
    ctl->ticket = 0u;
  }
}

// ---------------------------------------------------------------------------
extern "C" void kernel_launch(void* const* d_in, const int* in_sizes, int n_in,
                              void* d_out, int out_size, void* d_ws, size_t ws_size,
                              hipStream_t stream) {
  const float* p1 = (const float*)d_in[0];
  const float* p2 = (const float*)d_in[1];
  float* out = (float*)d_out;

  char* ws = (char*)d_ws;
  float4* p2aug = (float4*)ws;                       // 128 KiB
  IcpCtl* ctl   = (IcpCtl*)(ws + 128*1024);          // ~120 B
  double* acc   = (double*)(ws + 128*1024 + 512);    // 128 B

  icp_prep<<<N_PTS/256, 256, 0, stream>>>(p2, p2aug, ctl, acc);
  for (int it = 0; it < ICP_STEPS; ++it)
    icp_iter<<<NB, 256, 0, stream>>>(p1, p2aug, ctl, acc, out);
}

// Round 8
// 841.853 us; speedup vs baseline: 1.8120x; 1.0009x over previous
//
#include <hip/hip_runtime.h>
#include <math.h>

#define N_PTS 8192
#define ICP_STEPS 21      // STEPLIM + 1 scan iterations
#define ICP_TOL 1e-4

#define NB 256            // one block per CU; block owns 32 queries
#define QPW 8             // queries per wave (lane-sliced candidates)
#define CHUNK 2048        // candidates staged in LDS per chunk (32 KiB)
#define NCHUNK 4          // 4 * 2048 = 8192

struct IcpCtl {
  double err;
  double Rc[9];     // cumulative rotation (row-major): pc = Rc*p1 + tc
  double tc[3];
  int done;
  unsigned ticket;  // reduce-completion ticket (selects solver block)
};

// ---------------------------------------------------------------------------
// prep: p2aug = (x,y,z,|b|^2) float4; ctl/acc reset (runs every replay)
// ---------------------------------------------------------------------------
__global__ __launch_bounds__(256) void icp_prep(const float* __restrict__ p2,
                                                float4* __restrict__ p2aug,
                                                IcpCtl* __restrict__ ctl,
                                                double* __restrict__ acc) {
  int t = blockIdx.x * 256 + threadIdx.x;   // grid covers exactly N_PTS
  float x = p2[3*t], y = p2[3*t+1], z = p2[3*t+2];
  p2aug[t] = make_float4(x, y, z, fmaf(x, x, fmaf(y, y, z*z)));
  if (t == 0) {
    ctl->err = 0.0; ctl->done = 0; ctl->ticket = 0u;
    #pragma unroll
    for (int i = 0; i < 9; ++i) ctl->Rc[i] = (i % 4 == 0) ? 1.0 : 0.0;
    ctl->tc[0] = ctl->tc[1] = ctl->tc[2] = 0.0;
    #pragma unroll
    for (int i = 0; i < 16; ++i) acc[i] = 0.0;
  }
}

// ---------------------------------------------------------------------------
// Register-only 3x3 Kabsch from raw sums (no runtime-indexed arrays -> no
// scratch). s[0]=sum dmin, s[1..3]=sum src, s[4..6]=sum dst, s[7..15]=sum
// src_i*dst_j. R = V diag(1,1,detV) U~^T == reference's sign-fixed SVD.
// ---------------------------------------------------------------------------
__device__ __forceinline__ void kabsch_solve(const double* s, double* R, double* T) {
  const double n = (double)N_PTS;
  const double c1x = s[1]/n, c1y = s[2]/n, c1z = s[3]/n;
  const double c2x = s[4]/n, c2y = s[5]/n, c2z = s[6]/n;
  const double h00 = s[7]  - n*c1x*c2x, h01 = s[8]  - n*c1x*c2y, h02 = s[9]  - n*c1x*c2z;
  const double h10 = s[10] - n*c1y*c2x, h11 = s[11] - n*c1y*c2y, h12 = s[12] - n*c1y*c2z;
  const double h20 = s[13] - n*c1z*c2x, h21 = s[14] - n*c1z*c2y, h22 = s[15] - n*c1z*c2z;

  double a00 = h00*h00 + h10*h10 + h20*h20;
  double a01 = h00*h01 + h10*h11 + h20*h21;
  double a02 = h00*h02 + h10*h12 + h20*h22;
  double a11 = h01*h01 + h11*h11 + h21*h21;
  double a12 = h01*h02 + h11*h12 + h21*h22;
  double a22 = h02*h02 + h12*h12 + h22*h22;

  double v00=1.0, v01=0.0, v02=0.0;
  double v10=0.0, v11=1.0, v12=0.0;
  double v20=0.0, v21=0.0, v22=1.0;

#define ROT3(app, aqq, apq, arp, arq, vpa, vqa, vpb, vqb, vpc, vqc)              \
  {                                                                              \
    double apq_ = apq;                                                           \
    if (fabs(apq_) > 1e-300) {                                                   \
      double tau = (aqq - app) / (2.0 * apq_);                                   \
      double tt  = (tau >= 0.0 ? 1.0 : -1.0) / (fabs(tau) + sqrt(1.0 + tau*tau));\
      double c_  = 1.0 / sqrt(1.0 + tt*tt), sn = tt * c_;                        \
      app -= tt * apq_;  aqq += tt * apq_;  apq = 0.0;                           \
      double t1 = arp, t2 = arq;                                                 \
      arp = c_*t1 - sn*t2;  arq = sn*t1 + c_*t2;                                 \
      t1 = vpa; t2 = vqa; vpa = c_*t1 - sn*t2; vqa = sn*t1 + c_*t2;              \
      t1 = vpb; t2 = vqb; vpb = c_*t1 - sn*t2; vqb = sn*t1 + c_*t2;              \
      t1 = vpc; t2 = vqc; vpc = c_*t1 - sn*t2; vqc = sn*t1 + c_*t2;              \
    }                                                                            \
  }

  #pragma unroll
  for (int sweep = 0; sweep < 6; ++sweep) {
    ROT3(a00, a11, a01, a02, a12, v00, v01, v10, v11, v20, v21);  // (0,1)
    ROT3(a00, a22, a02, a01, a12, v00, v02, v10, v12, v20, v22);  // (0,2)
    ROT3(a11, a22, a12, a01, a02, v01, v02, v11, v12, v21, v22);  // (1,2)
  }
#undef ROT3

  double l0 = a00, l1 = a11, l2 = a22;
  double e0x=v00, e0y=v10, e0z=v20;
  double e1x=v01, e1y=v11, e1z=v21;
  double e2x=v02, e2y=v12, e2z=v22;
#define CSWAP(la, lb, xa, ya, za, xb, yb, zb)                                    \
  if (lb > la) { double t_;                                                      \
    t_ = la; la = lb; lb = t_;  t_ = xa; xa = xb; xb = t_;                       \
    t_ = ya; ya = yb; yb = t_;  t_ = za; za = zb; zb = t_; }
  CSWAP(l0, l1, e0x, e0y, e0z, e1x, e1y, e1z);
  CSWAP(l0, l2, e0x, e0y, e0z, e2x, e2y, e2z);
  CSWAP(l1, l2, e1x, e1y, e1z, e2x, e2y, e2z);
#undef CSWAP

  double detV = e0x*(e1y*e2z - e1z*e2y) - e0y*(e1x*e2z - e1z*e2x)
              + e0z*(e1x*e2y - e1y*e2x);
  const double dsg = (detV >= 0.0) ? 1.0 : -1.0;

  double u0x = h00*e0x + h01*e0y + h02*e0z;
  double u0y = h10*e0x + h11*e0y + h12*e0z;
  double u0z = h20*e0x + h21*e0y + h22*e0z;
  double n0 = sqrt(u0x*u0x + u0y*u0y + u0z*u0z);
  if (!(n0 > 1e-150)) {
    R[0]=1.0; R[1]=0.0; R[2]=0.0; R[3]=0.0; R[4]=1.0; R[5]=0.0;
    R[6]=0.0; R[7]=0.0; R[8]=1.0;
    T[0]=c2x-c1x; T[1]=c2y-c1y; T[2]=c2z-c1z;
    return;
  }
  u0x /= n0; u0y /= n0; u0z /= n0;
  double u1x = h00*e1x + h01*e1y + h02*e1z;
  double u1y = h10*e1x + h11*e1y + h12*e1z;
  double u1z = h20*e1x + h21*e1y + h22*e1z;
  const double d10 = u1x*u0x + u1y*u0y + u1z*u0z;
  u1x -= d10*u0x; u1y -= d10*u0y; u1z -= d10*u0z;
  double n1 = sqrt(u1x*u1x + u1y*u1y + u1z*u1z);
  if (!(n1 > 1e-150)) {
    R[0]=1.0; R[1]=0.0; R[2]=0.0; R[3]=0.0; R[4]=1.0; R[5]=0.0;
    R[6]=0.0; R[7]=0.0; R[8]=1.0;
    T[0]=c2x-c1x; T[1]=c2y-c1y; T[2]=c2z-c1z;
    return;
  }
  u1x /= n1; u1y /= n1; u1z /= n1;
  const double u2x = u0y*u1z - u0z*u1y;
  const double u2y = u0z*u1x - u0x*u1z;
  const double u2z = u0x*u1y - u0y*u1x;

  R[0] = e0x*u0x + e1x*u1x + dsg*e2x*u2x;
  R[1] = e0x*u0y + e1x*u1y + dsg*e2x*u2y;
  R[2] = e0x*u0z + e1x*u1z + dsg*e2x*u2z;
  R[3] = e0y*u0x + e1y*u1x + dsg*e2y*u2x;
  R[4] = e0y*u0y + e1y*u1y + dsg*e2y*u2y;
  R[5] = e0y*u0z + e1y*u1z + dsg*e2y*u2z;
  R[6] = e0z*u0x + e1z*u1x + dsg*e2z*u2x;
  R[7] = e0z*u0y + e1z*u1y + dsg*e2z*u2y;
  R[8] = e0z*u0z + e1z*u1z + dsg*e2z*u2z;
  T[0] = c2x - (R[0]*c1x + R[1]*c1y + R[2]*c1z);
  T[1] = c2y - (R[3]*c1x + R[4]*c1y + R[5]*c1z);
  T[2] = c2z - (R[6]*c1x + R[7]*c1y + R[8]*c1z);
}

// ---------------------------------------------------------------------------
// One fused ICP iteration (one dispatch). Identical to R7 EXCEPT
// __launch_bounds__(256, 1): min 1 wave/EU -> VGPR budget up to 512.
// R7's implicit high-occupancy target capped VGPRs at 60 and spilled the
// NN inner-loop state (~100 live regs) to scratch -> 8.2 MB/dispatch of
// spill traffic (the mysterious WRITE_SIZE) and 66 us dispatches. Grid is
// 1 block/CU anyway, so the occupancy cap costs nothing.
// ---------------------------------------------------------------------------
__global__ __launch_bounds__(256, 1) void icp_iter(const float* __restrict__ p1,
                                                   const float4* __restrict__ p2aug,
                                                   IcpCtl* __restrict__ ctl,
                                                   double* __restrict__ acc,
                                                   float* __restrict__ out) {
  if (ctl->done) return;                    // uniform across grid
  __shared__ float4 cand[CHUNK];            // 32 KiB
  __shared__ double pairbuf[32][17];        // +1 pad: conflict-free columns
  __shared__ double tot[16];
  __shared__ int lastFlag;

  const int tid  = threadIdx.x;
  const int lane = tid & 63;
  const int w    = tid >> 6;

  const double R0 = ctl->Rc[0], R1 = ctl->Rc[1], R2 = ctl->Rc[2];
  const double R3 = ctl->Rc[3], R4 = ctl->Rc[4], R5 = ctl->Rc[5];
  const double R6 = ctl->Rc[6], R7 = ctl->Rc[7], R8 = ctl->Rc[8];
  const double T0 = ctl->tc[0], T1 = ctl->tc[1], T2 = ctl->tc[2];

  // ---- wave w owns queries qbase..qbase+7 (uniform across its lanes) ----
  const int qbase = (blockIdx.x << 5) + (w << 3);
  float qx[QPW], qy[QPW], qz[QPW], axv[QPW], ayv[QPW], azv[QPW], best[QPW];
  int bidx[QPW];
  #pragma unroll
  for (int j = 0; j < QPW; ++j) {
    const int q = qbase + j;
    const double X = (double)p1[3*q], Y = (double)p1[3*q+1], Z = (double)p1[3*q+2];
    qx[j] = (float)(R0*X + R1*Y + R2*Z + T0);   // fp32-rounded, matches ref pc
    qy[j] = (float)(R3*X + R4*Y + R5*Z + T1);
    qz[j] = (float)(R6*X + R7*Y + R8*Z + T2);
    axv[j] = -2.f*qx[j]; ayv[j] = -2.f*qy[j]; azv[j] = -2.f*qz[j];
    best[j] = __builtin_inff(); bidx[j] = 0;
  }

  // ---- NN scan: 4 chunks of 2048 candidates, reg-prefetch next chunk ----
  float4 pf[8];
  #pragma unroll
  for (int k = 0; k < 8; ++k) pf[k] = p2aug[(k << 8) + tid];
  for (int cb = 0; cb < NCHUNK; ++cb) {
    #pragma unroll
    for (int k = 0; k < 8; ++k) cand[(k << 8) + tid] = pf[k];
    __syncthreads();
    if (cb + 1 < NCHUNK) {
      #pragma unroll
      for (int k = 0; k < 8; ++k)
        pf[k] = p2aug[((cb + 1) << 11) + (k << 8) + tid];
    }
    const int cbase = cb << 11;
    #pragma unroll 8
    for (int k = 0; k < 32; ++k) {
      float4 c = cand[(k << 6) + lane];     // lane-contiguous b128: no conflict
      const int cidx = cbase + (k << 6) + lane;
      #pragma unroll
      for (int j = 0; j < QPW; ++j) {
        float d = fmaf(axv[j], c.x, fmaf(ayv[j], c.y, fmaf(azv[j], c.z, c.w)));
        if (d < best[j]) { best[j] = d; bidx[j] = cidx; }
      }
    }
    __syncthreads();
  }

  // ---- cross-lane argmin: packed (ordered-dist, idx) u64 butterfly ----
  // jnp.argmin tie semantics: lowest distance, then lowest index.
  unsigned long long pk[QPW];
  #pragma unroll
  for (int j = 0; j < QPW; ++j) {
    unsigned u = __float_as_uint(best[j]);
    u ^= (unsigned)((int)u >> 31) | 0x80000000u;   // monotone float->uint
    pk[j] = ((unsigned long long)u << 32) | (unsigned)bidx[j];
  }
  #pragma unroll
  for (int j = 0; j < QPW; ++j) {
    #pragma unroll
    for (int o = 1; o < 64; o <<= 1) {
      unsigned long long other = __shfl_xor(pk[j], o, 64);
      pk[j] = (other < pk[j]) ? other : pk[j];
    }
  }

  // ---- pair sums: lane j<8 of each wave handles its query j ----
  if (lane < QPW) {
    const int j = lane;
    const unsigned idx = (unsigned)(pk[j] & 0xffffffffull);
    float4 b4 = p2aug[idx];
    double ax = qx[j], ay = qy[j], az = qz[j];
    double bx = b4.x, by = b4.y, bz = b4.z;
    double d2 = (ax*ax + ay*ay + az*az) + (bx*bx + by*by + bz*bz)
              - 2.0*(ax*bx + ay*by + az*bz);
    double* pb = pairbuf[(w << 3) + j];
    pb[0]  = sqrt(fmax(d2, 1e-12));
    pb[1]  = ax;    pb[2]  = ay;    pb[3]  = az;
    pb[4]  = bx;    pb[5]  = by;    pb[6]  = bz;
    pb[7]  = ax*bx; pb[8]  = ax*by; pb[9]  = ax*bz;
    pb[10] = ay*bx; pb[11] = ay*by; pb[12] = ay*bz;
    pb[13] = az*bx; pb[14] = az*by; pb[15] = az*bz;
  }
  __syncthreads();

  // ---- 16 column sums -> RELAXED memory-side atomicAdd (no fence) ----
  if (tid < 16) {
    double s = 0.0;
    #pragma unroll
    for (int i = 0; i < 32; ++i) s += pairbuf[i][tid];
    atomicAdd(acc + tid, s);                // device-scope, relaxed, memory-side
  }
  if (tid == 0) {
    // Same wave (lanes 0-15) issued the adds; vmcnt is per-wave, so this
    // waits for their completion at the coherence point. A WAIT, not a flush.
    asm volatile("s_waitcnt vmcnt(0)" ::: "memory");
    unsigned old = __hip_atomic_fetch_add(&ctl->ticket, 1u,
                      __ATOMIC_RELAXED, __HIP_MEMORY_SCOPE_AGENT);
    lastFlag = (old == NB - 1u) ? 1 : 0;
  }
  __syncthreads();
  if (!lastFlag) return;

  // ---- last block: totals via relaxed RMW read (memory-side, R2-proven) ----
  if (tid < 16) tot[tid] = atomicAdd(acc + tid, 0.0);
  __syncthreads();
  if (tid == 0) {
    double s[16];
    #pragma unroll
    for (int i = 0; i < 16; ++i) s[i] = tot[i];
    double R[9], T[3];
    kabsch_solve(s, R, T);
    // compose: pc_new = R*(Rc*p1 + tc) + T = (R*Rc)*p1 + (R*tc + T)
    double Rc[9] = {R0,R1,R2,R3,R4,R5,R6,R7,R8};
    double tc[3] = {T0,T1,T2};
    double Rn[9], tn[3];
    #pragma unroll
    for (int i = 0; i < 3; ++i) {
      #pragma unroll
      for (int j = 0; j < 3; ++j)
        Rn[3*i+j] = R[3*i+0]*Rc[0+j] + R[3*i+1]*Rc[3+j] + R[3*i+2]*Rc[6+j];
      tn[i] = R[3*i+0]*tc[0] + R[3*i+1]*tc[1] + R[3*i+2]*tc[2] + T[i];
    }
    #pragma unroll
    for (int i = 0; i < 9; ++i) ctl->Rc[i] = Rn[i];
    #pragma unroll
    for (int i = 0; i < 3; ++i) ctl->tc[i] = tn[i];
    double errnew = s[0];                   // B == 1
    ctl->done = (fabs(ctl->err - errnew) < ICP_TOL) ? 1 : 0;
    ctl->err  = errnew;
    // out = [Rc | tc] 3x4 (kabsch(p1, Rc*p1+tc) == (Rc,tc) exactly).
    #pragma unroll
    for (int i = 0; i < 3; ++i) {
      out[4*i + 0] = (float)Rn[3*i + 0];
      out[4*i + 1] = (float)Rn[3*i + 1];
      out[4*i + 2] = (float)Rn[3*i + 2];
      out[4*i + 3] = (float)tn[i];
    }
    // reset for next dispatch; end-of-kernel release makes these visible
    #pragma unroll
    for (int i = 0; i < 16; ++i) acc[i] = 0.0;
    ctl->ticket = 0u;
  }
}

// ---------------------------------------------------------------------------
extern "C" void kernel_launch(void* const* d_in, const int* in_sizes, int n_in,
                              void* d_out, int out_size, void* d_ws, size_t ws_size,
                              hipStream_t stream) {
  const float* p1 = (const float*)d_in[0];
  const float* p2 = (const float*)d_in[1];
  float* out = (float*)d_out;

  char* ws = (char*)d_ws;
  float4* p2aug = (float4*)ws;                       // 128 KiB
  IcpCtl* ctl   = (IcpCtl*)(ws + 128*1024);          // ~120 B
  double* acc   = (double*)(ws + 128*1024 + 512);    // 128 B

  icp_prep<<<N_PTS/256, 256, 0, stream>>>(p2, p2aug, ctl, acc);
  for (int it = 0; it < ICP_STEPS; ++it)
    icp_iter<<<NB, 256, 0, stream>>>(p1, p2aug, ctl, acc, out);
}

// Round 9
// 552.170 us; speedup vs baseline: 2.7626x; 1.5246x over previous
//
#include <hip/hip_runtime.h>
#include <math.h>

#define N_PTS 8192
#define ICP_STEPS 21      // STEPLIM + 1 scan iterations
#define ICP_TOL 1e-4

#define NBLK 256          // one block per CU; block owns 32 queries
#define BSIZE 1024        // 16 waves = 4 waves/SIMD (TLP for latency hiding)
#define QPW 8             // queries per wave-subgroup (8-way ILP, proven)

struct IcpCtl {
  double err;
  double Rc[9];     // cumulative rotation (row-major): pc = Rc*p1 + tc
  double tc[3];
  int done;
};

// ---------------------------------------------------------------------------
// prep: p2aug = (x,y,z,|b|^2) float4; ctl reset (runs every replay)
// ---------------------------------------------------------------------------
__global__ __launch_bounds__(256) void icp_prep(const float* __restrict__ p2,
                                                float4* __restrict__ p2aug,
                                                IcpCtl* __restrict__ ctl) {
  int t = blockIdx.x * 256 + threadIdx.x;   // grid covers exactly N_PTS
  float x = p2[3*t], y = p2[3*t+1], z = p2[3*t+2];
  p2aug[t] = make_float4(x, y, z, fmaf(x, x, fmaf(y, y, z*z)));
  if (t == 0) {
    ctl->err = 0.0; ctl->done = 0;
    #pragma unroll
    for (int i = 0; i < 9; ++i) ctl->Rc[i] = (i % 4 == 0) ? 1.0 : 0.0;
    ctl->tc[0] = ctl->tc[1] = ctl->tc[2] = 0.0;
  }
}

// ---------------------------------------------------------------------------
// Register-only 3x3 Kabsch from raw sums (no runtime-indexed arrays).
// s[0]=sum dmin, s[1..3]=sum src, s[4..6]=sum dst, s[7..15]=sum src_i*dst_j.
// R = V diag(1,1,detV) U~^T (right-handed U~) == reference's sign-fixed SVD.
// ---------------------------------------------------------------------------
__device__ __forceinline__ void kabsch_solve(const double* s, double* R, double* T) {
  const double n = (double)N_PTS;
  const double c1x = s[1]/n, c1y = s[2]/n, c1z = s[3]/n;
  const double c2x = s[4]/n, c2y = s[5]/n, c2z = s[6]/n;
  const double h00 = s[7]  - n*c1x*c2x, h01 = s[8]  - n*c1x*c2y, h02 = s[9]  - n*c1x*c2z;
  const double h10 = s[10] - n*c1y*c2x, h11 = s[11] - n*c1y*c2y, h12 = s[12] - n*c1y*c2z;
  const double h20 = s[13] - n*c1z*c2x, h21 = s[14] - n*c1z*c2y, h22 = s[15] - n*c1z*c2z;

  double a00 = h00*h00 + h10*h10 + h20*h20;
  double a01 = h00*h01 + h10*h11 + h20*h21;
  double a02 = h00*h02 + h10*h12 + h20*h22;
  double a11 = h01*h01 + h11*h11 + h21*h21;
  double a12 = h01*h02 + h11*h12 + h21*h22;
  double a22 = h02*h02 + h12*h12 + h22*h22;

  double v00=1.0, v01=0.0, v02=0.0;
  double v10=0.0, v11=1.0, v12=0.0;
  double v20=0.0, v21=0.0, v22=1.0;

#define ROT3(app, aqq, apq, arp, arq, vpa, vqa, vpb, vqb, vpc, vqc)              \
  {                                                                              \
    double apq_ = apq;                                                           \
    if (fabs(apq_) > 1e-300) {                                                   \
      double tau = (aqq - app) / (2.0 * apq_);                                   \
      double tt  = (tau >= 0.0 ? 1.0 : -1.0) / (fabs(tau) + sqrt(1.0 + tau*tau));\
      double c_  = 1.0 / sqrt(1.0 + tt*tt), sn = tt * c_;                        \
      app -= tt * apq_;  aqq += tt * apq_;  apq = 0.0;                           \
      double t1 = arp, t2 = arq;                                                 \
      arp = c_*t1 - sn*t2;  arq = sn*t1 + c_*t2;                                 \
      t1 = vpa; t2 = vqa; vpa = c_*t1 - sn*t2; vqa = sn*t1 + c_*t2;              \
      t1 = vpb; t2 = vqb; vpb = c_*t1 - sn*t2; vqb = sn*t1 + c_*t2;              \
      t1 = vpc; t2 = vqc; vpc = c_*t1 - sn*t2; vqc = sn*t1 + c_*t2;              \
    }                                                                            \
  }

  #pragma unroll
  for (int sweep = 0; sweep < 6; ++sweep) {
    ROT3(a00, a11, a01, a02, a12, v00, v01, v10, v11, v20, v21);  // (0,1)
    ROT3(a00, a22, a02, a01, a12, v00, v02, v10, v12, v20, v22);  // (0,2)
    ROT3(a11, a22, a12, a01, a02, v01, v02, v11, v12, v21, v22);  // (1,2)
  }
#undef ROT3

  double l0 = a00, l1 = a11, l2 = a22;
  double e0x=v00, e0y=v10, e0z=v20;
  double e1x=v01, e1y=v11, e1z=v21;
  double e2x=v02, e2y=v12, e2z=v22;
#define CSWAP(la, lb, xa, ya, za, xb, yb, zb)                                    \
  if (lb > la) { double t_;                                                      \
    t_ = la; la = lb; lb = t_;  t_ = xa; xa = xb; xb = t_;                       \
    t_ = ya; ya = yb; yb = t_;  t_ = za; za = zb; zb = t_; }
  CSWAP(l0, l1, e0x, e0y, e0z, e1x, e1y, e1z);
  CSWAP(l0, l2, e0x, e0y, e0z, e2x, e2y, e2z);
  CSWAP(l1, l2, e1x, e1y, e1z, e2x, e2y, e2z);
#undef CSWAP

  double detV = e0x*(e1y*e2z - e1z*e2y) - e0y*(e1x*e2z - e1z*e2x)
              + e0z*(e1x*e2y - e1y*e2x);
  const double dsg = (detV >= 0.0) ? 1.0 : -1.0;

  double u0x = h00*e0x + h01*e0y + h02*e0z;
  double u0y = h10*e0x + h11*e0y + h12*e0z;
  double u0z = h20*e0x + h21*e0y + h22*e0z;
  double n0 = sqrt(u0x*u0x + u0y*u0y + u0z*u0z);
  if (!(n0 > 1e-150)) {
    R[0]=1.0; R[1]=0.0; R[2]=0.0; R[3]=0.0; R[4]=1.0; R[5]=0.0;
    R[6]=0.0; R[7]=0.0; R[8]=1.0;
    T[0]=c2x-c1x; T[1]=c2y-c1y; T[2]=c2z-c1z;
    return;
  }
  u0x /= n0; u0y /= n0; u0z /= n0;
  double u1x = h00*e1x + h01*e1y + h02*e1z;
  double u1y = h10*e1x + h11*e1y + h12*e1z;
  double u1z = h20*e1x + h21*e1y + h22*e1z;
  const double d10 = u1x*u0x + u1y*u0y + u1z*u0z;
  u1x -= d10*u0x; u1y -= d10*u0y; u1z -= d10*u0z;
  double n1 = sqrt(u1x*u1x + u1y*u1y + u1z*u1z);
  if (!(n1 > 1e-150)) {
    R[0]=1.0; R[1]=0.0; R[2]=0.0; R[3]=0.0; R[4]=1.0; R[5]=0.0;
    R[6]=0.0; R[7]=0.0; R[8]=1.0;
    T[0]=c2x-c1x; T[1]=c2y-c1y; T[2]=c2z-c1z;
    return;
  }
  u1x /= n1; u1y /= n1; u1z /= n1;
  const double u2x = u0y*u1z - u0z*u1y;
  const double u2y = u0z*u1x - u0x*u1z;
  const double u2z = u0x*u1y - u0y*u1x;

  R[0] = e0x*u0x + e1x*u1x + dsg*e2x*u2x;
  R[1] = e0x*u0y + e1x*u1y + dsg*e2x*u2y;
  R[2] = e0x*u0z + e1x*u1z + dsg*e2x*u2z;
  R[3] = e0y*u0x + e1y*u1x + dsg*e2y*u2x;
  R[4] = e0y*u0y + e1y*u1y + dsg*e2y*u2y;
  R[5] = e0y*u0z + e1y*u1z + dsg*e2y*u2z;
  R[6] = e0z*u0x + e1z*u1x + dsg*e2z*u2x;
  R[7] = e0z*u0y + e1z*u1y + dsg*e2z*u2y;
  R[8] = e0z*u0z + e1z*u1z + dsg*e2z*u2z;
  T[0] = c2x - (R[0]*c1x + R[1]*c1y + R[2]*c1z);
  T[1] = c2y - (R[3]*c1x + R[4]*c1y + R[5]*c1z);
  T[2] = c2z - (R[6]*c1x + R[7]*c1y + R[8]*c1z);
}

// ---------------------------------------------------------------------------
// NN + partial sums (one dispatch per iteration). 1024 threads = 16 waves.
// Wave w = (g = w>>2, s = w&3): query subgroup g (8 queries, 8-way ILP),
// candidate slice s (2048 candidates). All candidates staged in LDS once.
// No atomics, no runtime-indexed register arrays (everything static ->
// no scratch). Block output: 16 plain-store partial sums to part[bid].
// ---------------------------------------------------------------------------
__global__ __launch_bounds__(BSIZE, 4) void icp_iter(const float* __restrict__ p1,
                                                     const float4* __restrict__ p2aug,
                                                     const IcpCtl* __restrict__ ctl,
                                                     double* __restrict__ part) {
  if (ctl->done) return;                    // uniform across grid
  __shared__ float4 cand[N_PTS];            // 128 KiB
  __shared__ unsigned long long pkbuf[32][4];
  __shared__ float4 qlds[32];
  __shared__ double pairbuf[32][17];        // +1 pad

  const int tid  = threadIdx.x;
  const int lane = tid & 63;
  const int w    = tid >> 6;
  const int g    = w >> 2;                  // query subgroup 0..3
  const int s    = w & 3;                   // candidate slice 0..3

  // ---- stage ALL candidates into LDS (each thread 8 float4, coalesced) ----
  #pragma unroll
  for (int k = 0; k < 8; ++k) {
    const int i = (k << 10) + tid;
    cand[i] = p2aug[i];
  }

  // ---- query transforms (wave-uniform; done while staging is in flight) ----
  const double R0 = ctl->Rc[0], R1 = ctl->Rc[1], R2 = ctl->Rc[2];
  const double R3 = ctl->Rc[3], R4 = ctl->Rc[4], R5 = ctl->Rc[5];
  const double R6 = ctl->Rc[6], R7 = ctl->Rc[7], R8 = ctl->Rc[8];
  const double T0 = ctl->tc[0], T1 = ctl->tc[1], T2 = ctl->tc[2];

  const int qbase = (blockIdx.x << 5) + (g << 3);
  float axv[QPW], ayv[QPW], azv[QPW], best[QPW];
  int bidx[QPW];
  float qxr[QPW], qyr[QPW], qzr[QPW];       // static-indexed only
  #pragma unroll
  for (int j = 0; j < QPW; ++j) {
    const int q = qbase + j;
    const double X = (double)p1[3*q], Y = (double)p1[3*q+1], Z = (double)p1[3*q+2];
    qxr[j] = (float)(R0*X + R1*Y + R2*Z + T0);  // fp32-rounded, matches ref pc
    qyr[j] = (float)(R3*X + R4*Y + R5*Z + T1);
    qzr[j] = (float)(R6*X + R7*Y + R8*Z + T2);
    axv[j] = -2.f*qxr[j]; ayv[j] = -2.f*qyr[j]; azv[j] = -2.f*qzr[j];
    best[j] = __builtin_inff(); bidx[j] = 0;
  }
  // publish query coords for the pair-sum phase (static unroll, lane 0 of s==0)
  if (s == 0 && lane == 0) {
    #pragma unroll
    for (int j = 0; j < QPW; ++j)
      qlds[(g << 3) + j] = make_float4(qxr[j], qyr[j], qzr[j], 0.f);
  }
  __syncthreads();

  // ---- NN scan: slice s = cands [s*2048, s*2048+2048), lane-contiguous ----
  const int cb = s << 11;
  #pragma unroll 8
  for (int k = 0; k < 32; ++k) {
    const int cidx = cb + (k << 6) + lane;
    float4 c = cand[cidx];                  // ds_read_b128, conflict-free
    #pragma unroll
    for (int j = 0; j < QPW; ++j) {
      float d = fmaf(axv[j], c.x, fmaf(ayv[j], c.y, fmaf(azv[j], c.z, c.w)));
      if (d < best[j]) { best[j] = d; bidx[j] = cidx; }
    }
  }

  // ---- cross-lane argmin: packed (ordered-dist, idx) u64 butterfly ----
  // jnp.argmin tie semantics: lowest distance, then lowest index.
  unsigned long long pk[QPW];
  #pragma unroll
  for (int j = 0; j < QPW; ++j) {
    unsigned u = __float_as_uint(best[j]);
    u ^= (unsigned)((int)u >> 31) | 0x80000000u;   // monotone float->uint
    pk[j] = ((unsigned long long)u << 32) | (unsigned)bidx[j];
  }
  #pragma unroll
  for (int j = 0; j < QPW; ++j) {
    #pragma unroll
    for (int o = 1; o < 64; o <<= 1) {
      unsigned long long other = __shfl_xor(pk[j], o, 64);
      pk[j] = (other < pk[j]) ? other : pk[j];
    }
  }
  if (lane == 0) {                          // static unroll -> registers
    #pragma unroll
    for (int j = 0; j < QPW; ++j)
      pkbuf[(g << 3) + j][s] = pk[j];
  }
  __syncthreads();

  // ---- combine 4 slices + pair sums: tid<32, one query each, all static ----
  if (tid < 32) {
    unsigned long long m = pkbuf[tid][0];
    unsigned long long m1 = pkbuf[tid][1]; m = (m1 < m) ? m1 : m;
    unsigned long long m2 = pkbuf[tid][2]; m = (m2 < m) ? m2 : m;
    unsigned long long m3 = pkbuf[tid][3]; m = (m3 < m) ? m3 : m;
    const unsigned idx = (unsigned)(m & 0xffffffffull);
    const float4 q4 = qlds[tid];
    const float4 b4 = cand[idx];            // LDS gather (32 lanes, cheap)
    const double ax = q4.x, ay = q4.y, az = q4.z;
    const double bx = b4.x, by = b4.y, bz = b4.z;
    const double d2 = (ax*ax + ay*ay + az*az) + (bx*bx + by*by + bz*bz)
                    - 2.0*(ax*bx + ay*by + az*bz);
    pairbuf[tid][0]  = sqrt(fmax(d2, 1e-12));
    pairbuf[tid][1]  = ax;    pairbuf[tid][2]  = ay;    pairbuf[tid][3]  = az;
    pairbuf[tid][4]  = bx;    pairbuf[tid][5]  = by;    pairbuf[tid][6]  = bz;
    pairbuf[tid][7]  = ax*bx; pairbuf[tid][8]  = ax*by; pairbuf[tid][9]  = ax*bz;
    pairbuf[tid][10] = ay*bx; pairbuf[tid][11] = ay*by; pairbuf[tid][12] = ay*bz;
    pairbuf[tid][13] = az*bx; pairbuf[tid][14] = az*by; pairbuf[tid][15] = az*bz;
  }
  __syncthreads();

  // ---- 16 column sums -> plain stores (coherent at kernel boundary) ----
  if (tid < 16) {
    double ssum = 0.0;
    #pragma unroll
    for (int i = 0; i < 32; ++i) ssum += pairbuf[i][tid];
    part[(blockIdx.x << 4) + tid] = ssum;
  }
}

// 16-value double block reduction (256 threads = 4 waves); result in tot[16]
__device__ __forceinline__ void block_reduce16(double* v, double* tot, double* lds) {
  const int lane = threadIdx.x & 63;
  const int w    = threadIdx.x >> 6;
  #pragma unroll
  for (int q = 0; q < 16; ++q) {
    double x = v[q];
    for (int o = 32; o > 0; o >>= 1) x += __shfl_down(x, o, 64);
    if (lane == 0) lds[w*16 + q] = x;
  }
  __syncthreads();
  if (threadIdx.x < 16)
    tot[threadIdx.x] = lds[threadIdx.x] + lds[16 + threadIdx.x]
                     + lds[32 + threadIdx.x] + lds[48 + threadIdx.x];
  __syncthreads();
}

// ---------------------------------------------------------------------------
// solve (1 block): reduce 256 partial rows, Kabsch, compose transform,
// done-logic, write out. Kernel boundary provides coherence both ways.
// ---------------------------------------------------------------------------
__global__ __launch_bounds__(256) void icp_solve(IcpCtl* __restrict__ ctl,
                                                 const double* __restrict__ part,
                                                 float* __restrict__ out) {
  if (ctl->done) return;
  __shared__ double lds[64];
  __shared__ double tot[16];
  double v[16];
  const double* row = part + (threadIdx.x << 4);
  #pragma unroll
  for (int c = 0; c < 16; ++c) v[c] = row[c];
  block_reduce16(v, tot, lds);

  if (threadIdx.x == 0) {
    double s[16];
    #pragma unroll
    for (int i = 0; i < 16; ++i) s[i] = tot[i];
    double R[9], T[3];
    kabsch_solve(s, R, T);
    // compose: pc_new = R*(Rc*p1 + tc) + T = (R*Rc)*p1 + (R*tc + T)
    double Rc[9], tc[3], Rn[9], tn[3];
    #pragma unroll
    for (int i = 0; i < 9; ++i) Rc[i] = ctl->Rc[i];
    #pragma unroll
    for (int i = 0; i < 3; ++i) tc[i] = ctl->tc[i];
    #pragma unroll
    for (int i = 0; i < 3; ++i) {
      #pragma unroll
      for (int j = 0; j < 3; ++j)
        Rn[3*i+j] = R[3*i+0]*Rc[0+j] + R[3*i+1]*Rc[3+j] + R[3*i+2]*Rc[6+j];
      tn[i] = R[3*i+0]*tc[0] + R[3*i+1]*tc[1] + R[3*i+2]*tc[2] + T[i];
    }
    #pragma unroll
    for (int i = 0; i < 9; ++i) ctl->Rc[i] = Rn[i];
    #pragma unroll
    for (int i = 0; i < 3; ++i) ctl->tc[i] = tn[i];
    const double errnew = s[0];             // B == 1
    ctl->done = (fabs(ctl->err - errnew) < ICP_TOL) ? 1 : 0;
    ctl->err  = errnew;
    // out = [Rc | tc] 3x4 (kabsch(p1, Rc*p1+tc) == (Rc,tc) exactly).
    #pragma unroll
    for (int i = 0; i < 3; ++i) {
      out[4*i + 0] = (float)Rn[3*i + 0];
      out[4*i + 1] = (float)Rn[3*i + 1];
      out[4*i + 2] = (float)Rn[3*i + 2];
      out[4*i + 3] = (float)tn[i];
    }
  }
}

// ---------------------------------------------------------------------------
extern "C" void kernel_launch(void* const* d_in, const int* in_sizes, int n_in,
                              void* d_out, int out_size, void* d_ws, size_t ws_size,
                              hipStream_t stream) {
  const float* p1 = (const float*)d_in[0];
  const float* p2 = (const float*)d_in[1];
  float* out = (float*)d_out;

  char* ws = (char*)d_ws;
  float4* p2aug = (float4*)ws;                       // 128 KiB
  IcpCtl* ctl   = (IcpCtl*)(ws + 128*1024);          // ~112 B
  double* part  = (double*)(ws + 128*1024 + 512);    // 32 KiB (256 x 16 f64)

  icp_prep<<<N_PTS/256, 256, 0, stream>>>(p2, p2aug, ctl);
  for (int it = 0; it < ICP_STEPS; ++it) {
    icp_iter<<<NBLK, BSIZE, 0, stream>>>(p1, p2aug, ctl, part);
    icp_solve<<<1, 256, 0, stream>>>(ctl, part, out);
  }
}